// Round 3
// baseline (5647.763 us; speedup 1.0000x reference)
//
#include <hip/hip_runtime.h>

#define DI __device__ __forceinline__

typedef unsigned short u16;
typedef unsigned int u32;
typedef __bf16 bf16x8 __attribute__((ext_vector_type(8)));
typedef float f32x4 __attribute__((ext_vector_type(4)));

// Model dims
static constexpr int B = 256, Tn = 20, En = 96, Hn = 670, Vn = 10004;
static constexpr int HP = 672;            // padded hidden
static constexpr int NBLK = 256;          // k_loop grid size

DI float bf2f(u16 u) { union { u32 i; float f; } v; v.i = ((u32)u) << 16; return v.f; }
DI u16 f2bf(float f) {
    u32 u = __float_as_uint(f);
    u32 r = (u + 0x7FFFu + ((u >> 16) & 1u)) >> 16;
    return (u16)r;
}
DI float sigm(float x) { return 1.f / (1.f + __expf(-x)); }
DI float tanha(float x) {
    x = fminf(fmaxf(x, -15.f), 15.f);
    float e = __expf(2.f * x);
    return (e - 1.f) / (e + 1.f);
}
DI bf16x8 frag(const u16* p) { return *(const bf16x8*)p; }
DI f32x4 mfma16(bf16x8 a, bf16x8 b, f32x4 c) {
    return __builtin_amdgcn_mfma_f32_16x16x32_bf16(a, b, c, 0, 0, 0);
}
// flag-aware element loads (f=1 -> source is float32, f=0 -> bf16)
DI u16 ldw(const u16* src, long long i, int f) {
    return f ? f2bf(((const float*)src)[i]) : src[i];
}
DI float ldf(const u16* src, long long i, int f) {
    return f ? ((const float*)src)[i] : bf2f(src[i]);
}

struct Ptrs {
    const int* x;
    const u16 *emb, *g_wi, *g_wh, *g_bi, *g_bh, *l_wi, *l_wh, *l_bi, *l_bh;
    const u16 *gl1_w, *gl1_b, *ll1_w, *ll1_b, *gl2_w, *gl2_b, *ll2_w, *ll2_b;
    const u16 *p1_w, *p1_b, *p2_w, *p2_b, *p3_w, *p3_b, *p4_w, *p4_b, *pe_w, *pe_b;
    const u16 *q1_w, *q1_b, *q2_w, *q2_b, *q2e_w, *q2e_b, *q3_w, *q3_b, *q3e_w, *q3e_b;
    // scratch
    unsigned *bar; // [0]=broadcast flag line; [32 + bid*16]=per-block arrival slots (64B spaced)
    int  *flagp;  // [0] = 1 if inputs are float32
    u16 *embs;    // [T][B][96] bf16
    u16 *WgCat;   // [2][2680][768] bf16 : [wi(96) | wh(670) | pad]
    u16 *P1W;     // [512][1440] bf16
    u16 *W1C;     // [192][672] bf16
    u16 *W2C;     // [10112][192] bf16 : [gl2_w | ll2_w]
    float *BSUM;  // [2][2680] f32 bias sums
    u16 *hs;      // [5120][672] bf16 (row n = b*20+t)
    u16 *hcat;    // [2][B][1344] bf16 double-buffered
    u16 *uw;      // [5120][192] bf16
    float *ghf, *gcf, *lhf, *lc2, *gcm;
    float *L1out; // [B][500]
    float *sf;    // [5120][192]
    float *p2sbuf;// [5120][2]
    // normalized bf16 copies of small tensors
    u16 *n_p1b, *n_p2w, *n_p2b, *n_p3w, *n_p3b, *n_p4w, *n_p4b, *n_pew, *n_peb;
    u16 *n_gl1b, *n_ll1b, *n_gl2b, *n_ll2b;
    u16 *n_q1w, *n_q1b, *n_q2w, *n_q2b, *n_q2ew, *n_q2eb, *n_q3w, *n_q3b, *n_q3ew, *n_q3eb;
    u16 *out0, *out1;
    float *out0f, *out1f;
};

// ---------------- software grid barrier: distributed arrival slots ----------------
// Each block release-stores `gen` into its OWN 64B-spaced slot (parallel stores, no RMW
// contention). Block 0's 256 threads poll the 256 slots in parallel (overlapped latency),
// then release-store the broadcast flag; other blocks spin (read-only) on the flag.
// Wraparound-safe >= comparison so a fast block writing gen+1 can't strand the leader.
DI void gbar(unsigned* bar, int bid, int tid, unsigned gen) {
    unsigned* slots = bar + 32;
    __syncthreads();
    if (tid == 0) {
        __threadfence();   // release: make this block's prior writes device-visible
        __hip_atomic_store(&slots[bid * 16], gen, __ATOMIC_RELEASE, __HIP_MEMORY_SCOPE_AGENT);
    }
    if (bid == 0) {
        unsigned* my = &slots[tid * 16];
        while ((int)(__hip_atomic_load(my, __ATOMIC_ACQUIRE, __HIP_MEMORY_SCOPE_AGENT) - gen) < 0)
            __builtin_amdgcn_s_sleep(2);
        __syncthreads();
        if (tid == 0)
            __hip_atomic_store(bar, gen, __ATOMIC_RELEASE, __HIP_MEMORY_SCOPE_AGENT);
    } else if (tid == 0) {
        while ((int)(__hip_atomic_load(bar, __ATOMIC_ACQUIRE, __HIP_MEMORY_SCOPE_AGENT) - gen) < 0)
            __builtin_amdgcn_s_sleep(4);
    }
    __threadfence();       // acquire side: discard stale cached data
    __syncthreads();
}

// ------------- detect input dtype + init barrier -------------
__global__ __launch_bounds__(256) void k_detect(Ptrs p) {
    int tid = threadIdx.x;
    for (int i = tid; i < 4384; i += 256) p.bar[i] = 0u;
    if (tid < 64) {
        u32 d = ((const u32*)p.g_bi)[tid];   // first 64 dwords of g_bi
        u16 lo = (u16)(d & 0xffffu);
        int e = (lo >> 7) & 0xff;             // bf16 exponent field of the LOW u16
        unsigned long long m = __ballot(e >= 127);   // |x|>=1 impossible for bf16 N(0,.05) data
        if (tid == 0) p.flagp[0] = (m != 0ull) ? 1 : 0;
    }
}

// ---------------- shared-memory phase overlays ----------------
struct SMg { u16 Al[32 * 40]; u16 Wl[128 * 40]; float bs[128]; };
struct SMm { u16 Al[32 * 40]; u16 Wl[32 * 40]; };
struct SMr { float l1[500]; float h2s[250]; float h3s[100]; float h4s[52]; float pr[4]; };
struct SMs { u16 Al[64 * 40]; u16 Wl[64 * 40]; };
struct SMq {
    float sfl[3840];
    float h1[20][80]; float h2[20][32]; float h3[20][12];
    float yv[20][2]; float zv[20][2]; float p1s[20][2]; float p2sl[20][2];
};
union alignas(16) SMem { SMg g; SMm m; SMr r; SMs s; SMq q; };

// ---------------- phase: normalize small tensors (grid-stride) ----------------
DI void norm_phase(const Ptrs& p, int gtid, int f) {
    const u16* srcs[23] = {p.p1_b, p.p2_w, p.p2_b, p.p3_w, p.p3_b, p.p4_w, p.p4_b,
                           p.pe_w, p.pe_b, p.gl1_b, p.ll1_b, p.gl2_b, p.ll2_b,
                           p.q1_w, p.q1_b, p.q2_w, p.q2_b, p.q2e_w, p.q2e_b,
                           p.q3_w, p.q3_b, p.q3e_w, p.q3e_b};
    u16* dsts[23] = {p.n_p1b, p.n_p2w, p.n_p2b, p.n_p3w, p.n_p3b, p.n_p4w, p.n_p4b,
                     p.n_pew, p.n_peb, p.n_gl1b, p.n_ll1b, p.n_gl2b, p.n_ll2b,
                     p.n_q1w, p.n_q1b, p.n_q2w, p.n_q2b, p.n_q2ew, p.n_q2eb,
                     p.n_q3w, p.n_q3b, p.n_q3ew, p.n_q3eb};
    const int ns[23] = {500, 125000, 250, 25000, 100, 5000, 50, 100, 2, 96, 96, 10004, 10004,
                        14400, 75, 2250, 30, 60, 2, 300, 10, 20, 2};
    for (int i0 = gtid; i0 < 193351; i0 += 65536) {
        int i = i0;
        #pragma unroll 1
        for (int s = 0; s < 23; ++s) {
            if (i < ns[s]) { dsts[s][i] = ldw(srcs[s], i, f); break; }
            i -= ns[s];
        }
    }
}

// ---------------- phase: gather embeddings, pack/pad weights (grid-stride) ----------------
DI void prep_one(const Ptrs& p, int i, int f) {
    if (i < 491520) { // embs gather, elementwise
        int r = i / 96, j = i % 96;
        int t = r >> 8, b = r & 255;
        int idx = p.x[b * Tn + t];
        p.embs[r * 96 + j] = ldw(p.emb, (long long)idx * 96 + j, f);
        return;
    }
    i -= 491520;
    if (i < 2 * 2680 * 768) { // WgCat
        int z = i / (2680 * 768);
        int rem = i - z * (2680 * 768);
        int col = rem / 768, k = rem % 768;
        const u16* wi = z ? p.l_wi : p.g_wi;
        const u16* wh = z ? p.l_wh : p.g_wh;
        u16 v = 0;
        if (k < 96) v = ldw(wi, col * 96 + k, f);
        else { int j = k - 96; if (j < 670) v = ldw(wh, col * 670 + j, f); }
        p.WgCat[i] = v;
        return;
    }
    i -= 2 * 2680 * 768;
    if (i < 512 * 1440) { // P1W
        int col = i / 1440, k = i % 1440;
        u16 v = 0;
        if (col < 500) {
            if (k < 96) v = ldw(p.p1_w, col * 1436 + k, f);
            else if (k < 768) { int j = k - 96;  if (j < 670) v = ldw(p.p1_w, col * 1436 + 96 + j, f); }
            else              { int j = k - 768; if (j < 670) v = ldw(p.p1_w, col * 1436 + 766 + j, f); }
        }
        p.P1W[i] = v;
        return;
    }
    i -= 512 * 1440;
    if (i < 192 * 672) { // W1C
        int o = i / 672, h = i % 672;
        u16 v = 0;
        if (h < 670) v = (o < 96) ? ldw(p.gl1_w, o * 670 + h, f) : ldw(p.ll1_w, (o - 96) * 670 + h, f);
        p.W1C[i] = v;
        return;
    }
    i -= 192 * 672;
    if (i < 10112 * 192) { // W2C
        int v_ = i / 192, k = i % 192;
        u16 v = 0;
        if (v_ < Vn) v = (k < 96) ? ldw(p.gl2_w, v_ * 96 + k, f) : ldw(p.ll2_w, v_ * 96 + (k - 96), f);
        p.W2C[i] = v;
        return;
    }
    i -= 10112 * 192;
    if (i < 2 * 2680) { // BSUM
        int z = i / 2680, col = i % 2680;
        const u16* bi = z ? p.l_bi : p.g_bi;
        const u16* bh = z ? p.l_bh : p.g_bh;
        p.BSUM[i] = ldf(bi, col, f) + ldf(bh, col, f);
    }
}

// ------------- phase: fused gates GEMM + LSTM elementwise (one tile) -------------
DI void gates_tile(const Ptrs& p, int t, int tau, int tid, SMg& S) {
    const int z = tau / 168;
    const int rem = tau - z * 168;
    const int jt = rem % 21, mt = rem / 21;
    const int row0 = mt * 32, j0 = jt * 32;
    const int lane = tid & 63, wv = tid >> 6;

    __syncthreads();   // protect bs/Al/Wl reuse across consecutive tiles
    if (tid < 128) {
        int gate = tid >> 5, jj = tid & 31, j = j0 + jj;
        S.bs[tid] = (j < Hn) ? p.BSUM[z * 2680 + gate * Hn + j] : 0.f;
    }
    const int cur = t & 1, prv = cur ^ 1;
    f32x4 acc[4] = {};
    const int mtw = wv & 1, jh = wv >> 1;

    for (int kc = 0; kc < 24; ++kc) {
        const int kb = kc * 32;
        __syncthreads();
        if (tid < 128) {
            int r = tid >> 2, k8 = (tid & 3) * 8, k = kb + k8;
            int b = row0 + r;
            uint4 val = {0, 0, 0, 0};
            if (k < 96) val = *(const uint4*)&p.embs[(t * 256 + b) * 96 + k];
            else if (t > 0) {
                int kk = k - 96;
                const u16* src = (z == 0) ? (p.hs + (b * Tn + (t - 1)) * HP + kk)
                                          : (p.hcat + prv * (B * 1344) + b * 1344 + 672 + kk);
                val = *(const uint4*)src;
            }
            *(uint4*)&S.Al[r * 40 + k8] = val;
        }
        #pragma unroll
        for (int it = 0; it < 2; ++it) {
            int idx = tid + it * 256;
            int ri = idx >> 2, k8 = (idx & 3) * 8;
            int gate = ri >> 5, jj = ri & 31, j = j0 + jj;
            uint4 val = {0, 0, 0, 0};
            if (j < Hn) val = *(const uint4*)&p.WgCat[(z * 2680 + gate * Hn + j) * 768 + kb + k8];
            *(uint4*)&S.Wl[ri * 40 + k8] = val;
        }
        __syncthreads();
        bf16x8 a = frag(&S.Al[(mtw * 16 + (lane & 15)) * 40 + (lane >> 4) * 8]);
        #pragma unroll
        for (int g = 0; g < 4; ++g) {
            int nt = g * 2 + jh;
            bf16x8 bb = frag(&S.Wl[(nt * 16 + (lane & 15)) * 40 + (lane >> 4) * 8]);
            acc[g] = mfma16(a, bb, acc[g]);
        }
    }
    const int q = lane >> 4;
    const int jj = jh * 16 + (lane & 15);
    const int j = j0 + jj;
    const bool valid = (j < Hn);
    #pragma unroll
    for (int r = 0; r < 4; ++r) {
        int b = row0 + mtw * 16 + q * 4 + r;
        float I = fminf(fmaxf(acc[0][r] + S.bs[jj], -30.f), 30.f);
        float F = fminf(fmaxf(acc[1][r] + S.bs[32 + jj], -30.f), 30.f);
        float G = fminf(fmaxf(acc[2][r] + S.bs[64 + jj], -30.f), 30.f);
        float O = fminf(fmaxf(acc[3][r] + S.bs[96 + jj], -30.f), 30.f);
        float cp = 0.f;
        if (valid && t > 0)
            cp = (z == 0) ? p.gcm[b * Hn + j] : p.lc2[prv * (B * Hn) + b * Hn + j];
        float c = sigm(F) * cp + sigm(I) * tanha(G);
        float h = sigm(O) * tanha(c);
        if (z == 0) {
            if (valid) { p.ghf[b * Hn + j] = h; p.gcf[b * Hn + j] = c; }
            p.hcat[cur * (B * 1344) + b * 1344 + j] = valid ? f2bf(h) : (u16)0;
        } else {
            if (valid) { p.lhf[b * Hn + j] = h; p.lc2[cur * (B * Hn) + b * Hn + j] = c; }
            p.hcat[cur * (B * 1344) + b * 1344 + 672 + j] = valid ? f2bf(h) : (u16)0;
        }
    }
}

// ------------- phase: MLP layer 1 GEMM [256,1440]@[1440,512] (128 tiles 32x32) -------------
DI void mlp1_tile(const Ptrs& p, int t, int bid, int tid, SMm& S) {
    const int col0 = (bid & 15) * 32;
    const int row0 = (bid >> 4) * 32;
    const int lane = tid & 63, wv = tid >> 6;
    const int cur = t & 1;
    f32x4 acc = {};
    const int mtw = wv & 1, nh = wv >> 1;
    for (int kc = 0; kc < 45; ++kc) {
        const int kb = kc * 32;
        __syncthreads();
        if (tid < 128) {
            int r = tid >> 2, k8 = (tid & 3) * 8, k = kb + k8;
            int b = row0 + r;
            uint4 val;
            if (k < 96) val = *(const uint4*)&p.embs[(t * 256 + b) * 96 + k];
            else        val = *(const uint4*)&p.hcat[cur * (B * 1344) + b * 1344 + (k - 96)];
            *(uint4*)&S.Al[r * 40 + k8] = val;
        } else {
            int idx = tid - 128;
            int ri = idx >> 2, k8 = (idx & 3) * 8;
            *(uint4*)&S.Wl[ri * 40 + k8] = *(const uint4*)&p.P1W[(col0 + ri) * 1440 + kb + k8];
        }
        __syncthreads();
        bf16x8 a = frag(&S.Al[(mtw * 16 + (lane & 15)) * 40 + (lane >> 4) * 8]);
        bf16x8 bb = frag(&S.Wl[(nh * 16 + (lane & 15)) * 40 + (lane >> 4) * 8]);
        acc = mfma16(a, bb, acc);
    }
    const int q = lane >> 4;
    int col = col0 + nh * 16 + (lane & 15);
    if (col < 500) {
        float bias = bf2f(p.n_p1b[col]);
        #pragma unroll
        for (int r = 0; r < 4; ++r) {
            int b = row0 + mtw * 16 + q * 4 + r;
            p.L1out[b * 500 + col] = fmaxf(acc[r] + bias, 0.f);
        }
    }
}

// ------------- phase: MLP layers 2..5, softmax, mix, write hs/out1 -------------
DI void rest_block(const Ptrs& p, int t, int b, int tid, int f, SMr& S) {
    for (int i = tid; i < 125; i += 256)
        *(float4*)&S.l1[i * 4] = *(const float4*)&p.L1out[b * 500 + i * 4];
    __syncthreads();
    if (tid < 250) {
        const u16* wr = p.n_p2w + tid * 500;
        float s = 0.f;
        for (int k = 0; k < 500; k += 4) {
            uint2 u = *(const uint2*)&wr[k];
            s += S.l1[k]     * bf2f((u16)(u.x & 0xffff));
            s += S.l1[k + 1] * bf2f((u16)(u.x >> 16));
            s += S.l1[k + 2] * bf2f((u16)(u.y & 0xffff));
            s += S.l1[k + 3] * bf2f((u16)(u.y >> 16));
        }
        S.h2s[tid] = fmaxf(s + bf2f(p.n_p2b[tid]), 0.f);
    }
    __syncthreads();
    if (tid < 100) {
        const u16* wr = p.n_p3w + tid * 250;
        float s = 0.f;
        for (int k = 0; k < 250; k += 2) {
            u32 u = *(const u32*)&wr[k];
            s += S.h2s[k]     * bf2f((u16)(u & 0xffff));
            s += S.h2s[k + 1] * bf2f((u16)(u >> 16));
        }
        S.h3s[tid] = fmaxf(s + bf2f(p.n_p3b[tid]), 0.f);
    }
    __syncthreads();
    if (tid < 50) {
        const u16* wr = p.n_p4w + tid * 100;
        float s = 0.f;
        for (int k = 0; k < 100; k += 4) {
            uint2 u = *(const uint2*)&wr[k];
            s += S.h3s[k]     * bf2f((u16)(u.x & 0xffff));
            s += S.h3s[k + 1] * bf2f((u16)(u.x >> 16));
            s += S.h3s[k + 2] * bf2f((u16)(u.y & 0xffff));
            s += S.h3s[k + 3] * bf2f((u16)(u.y >> 16));
        }
        S.h4s[tid] = fmaxf(s + bf2f(p.n_p4b[tid]), 0.f);
    }
    __syncthreads();
    if (tid == 0) {
        float e0 = bf2f(p.n_peb[0]), e1 = bf2f(p.n_peb[1]);
        for (int k = 0; k < 50; ++k) {
            e0 += S.h4s[k] * bf2f(p.n_pew[k]);
            e1 += S.h4s[k] * bf2f(p.n_pew[50 + k]);
        }
        float m = fmaxf(e0, e1);
        float a0 = __expf(e0 - m), a1 = __expf(e1 - m);
        float inv = 1.f / (a0 + a1);
        S.pr[0] = a0 * inv; S.pr[1] = a1 * inv;
    }
    __syncthreads();
    float p0 = S.pr[0], p1 = S.pr[1];
    const int cur = t & 1;
    for (int j = tid; j < HP; j += 256) {
        u16 hv = 0;
        if (j < Hn) {
            float gm = p0 * p.lhf[b * Hn + j] + p1 * p.ghf[b * Hn + j];
            float cm = p0 * p.lc2[cur * (B * Hn) + b * Hn + j] + p1 * p.gcf[b * Hn + j];
            p.gcm[b * Hn + j] = cm;
            hv = f2bf(gm);
        }
        p.hs[(b * Tn + t) * HP + j] = hv;
    }
    if (tid < 40) {
        long long idx = b * 880 + t * 40 + tid;
        float v = (tid & 1) ? p1 : p0;
        if (f) p.out1f[idx] = v; else p.out1[idx] = f2bf(v);
    }
}

// ------------- phase: sf = hs @ [gl1;ll1]^T + bias  ([5120,672]@[672,192]) -------------
DI void sf_tile(const Ptrs& p, int tau, int tid, SMs& S) {
    const int col0 = (tau % 3) * 64;
    const int row0 = (tau / 3) * 64;
    const int lane = tid & 63, wv = tid >> 6;
    f32x4 acc[4] = {};
    for (int kc = 0; kc < 21; ++kc) {
        const int kb = kc * 32;
        __syncthreads();
        {
            int r = tid >> 2, k8 = (tid & 3) * 8;
            *(uint4*)&S.Al[r * 40 + k8] = *(const uint4*)&p.hs[(row0 + r) * HP + kb + k8];
            *(uint4*)&S.Wl[r * 40 + k8] = *(const uint4*)&p.W1C[(col0 + r) * HP + kb + k8];
        }
        __syncthreads();
        bf16x8 a = frag(&S.Al[(wv * 16 + (lane & 15)) * 40 + (lane >> 4) * 8]);
        #pragma unroll
        for (int nt = 0; nt < 4; ++nt) {
            bf16x8 bb = frag(&S.Wl[(nt * 16 + (lane & 15)) * 40 + (lane >> 4) * 8]);
            acc[nt] = mfma16(a, bb, acc[nt]);
        }
    }
    const int q = lane >> 4;
    #pragma unroll
    for (int nt = 0; nt < 4; ++nt) {
        int col = col0 + nt * 16 + (lane & 15);
        float bias = bf2f(col < 96 ? p.n_gl1b[col] : p.n_ll1b[col - 96]);
        #pragma unroll
        for (int r = 0; r < 4; ++r) {
            int row = row0 + wv * 16 + q * 4 + r;
            p.sf[row * 192 + col] = acc[nt][r] + bias;
        }
    }
}

// ------------- phase: per-batch q-chain, softmaxes, u/w, out1 rows 20/21 -------------
DI void qchain_block(const Ptrs& p, int b, int tid, int f, SMq& S) {
    for (int i = tid; i < 960; i += 256)
        *(float4*)&S.sfl[i * 4] = *(const float4*)&p.sf[b * 3840 + i * 4];
    __syncthreads();
    for (int u = tid; u < 1500; u += 256) {
        int row = u / 75, o = u % 75;
        const u16* wr = p.n_q1w + o * 192;
        const float* sr = &S.sfl[row * 192];
        float s = bf2f(p.n_q1b[o]);
        for (int k = 0; k < 192; k += 4) {
            uint2 w = *(const uint2*)&wr[k];
            s += sr[k]     * bf2f((u16)(w.x & 0xffff));
            s += sr[k + 1] * bf2f((u16)(w.x >> 16));
            s += sr[k + 2] * bf2f((u16)(w.y & 0xffff));
            s += sr[k + 3] * bf2f((u16)(w.y >> 16));
        }
        S.h1[row][o] = fmaxf(s, 0.f);
    }
    __syncthreads();
    for (int u = tid; u < 600; u += 256) {
        int row = u / 30, o = u % 30;
        const u16* wr = p.n_q2w + o * 75;
        float s = bf2f(p.n_q2b[o]);
        for (int k = 0; k < 75; ++k) s += S.h1[row][k] * bf2f(wr[k]);
        S.h2[row][o] = fmaxf(s, 0.f);
    }
    __syncthreads();
    if (tid < 40) {
        int row = tid >> 1, o = tid & 1;
        const u16* wr = p.n_q2ew + o * 30;
        float s = bf2f(p.n_q2eb[o]);
        for (int k = 0; k < 30; ++k) s += S.h2[row][k] * bf2f(wr[k]);
        S.yv[row][o] = fmaxf(s, 0.f);
    } else if (tid >= 56 && tid < 256) {
        int u = tid - 56;  // 200 units
        int row = u / 10, o = u % 10;
        const u16* wr = p.n_q3w + o * 30;
        float s = bf2f(p.n_q3b[o]);
        for (int k = 0; k < 30; ++k) s += S.h2[row][k] * bf2f(wr[k]);
        S.h3[row][o] = fmaxf(s, 0.f);
    }
    __syncthreads();
    if (tid < 40) {
        int row = tid >> 1, o = tid & 1;
        const u16* wr = p.n_q3ew + o * 10;
        float s = bf2f(p.n_q3eb[o]);
        for (int k = 0; k < 10; ++k) s += S.h3[row][k] * bf2f(wr[k]);
        S.zv[row][o] = fmaxf(s, 0.f);
    } else if (tid >= 64 && tid < 84) {
        int row = tid - 64;
        float m = fmaxf(S.yv[row][0], S.yv[row][1]);
        float a0 = __expf(S.yv[row][0] - m), a1 = __expf(S.yv[row][1] - m);
        float inv = 1.f / (a0 + a1);
        S.p1s[row][0] = a0 * inv; S.p1s[row][1] = a1 * inv;
    }
    __syncthreads();
    if (tid < 20) {
        float m = fmaxf(S.zv[tid][0], S.zv[tid][1]);
        float a0 = __expf(S.zv[tid][0] - m), a1 = __expf(S.zv[tid][1] - m);
        float inv = 1.f / (a0 + a1);
        S.p2sl[tid][0] = a0 * inv; S.p2sl[tid][1] = a1 * inv;
        p.p2sbuf[(b * Tn + tid) * 2]     = a0 * inv;
        p.p2sbuf[(b * Tn + tid) * 2 + 1] = a1 * inv;
    } else if (tid >= 64 && tid < 104) {
        int row = (tid - 64) >> 1, c = (tid - 64) & 1;
        long long idx = b * 880 + 800 + row * 2 + c;
        if (f) p.out1f[idx] = S.p1s[row][c]; else p.out1[idx] = f2bf(S.p1s[row][c]);
    }
    __syncthreads();
    for (int u = tid; u < 1920; u += 256) {
        int row = u / 96, e = u % 96;
        float xm = S.p1s[row][0] * S.sfl[row * 192 + e] + S.p1s[row][1] * S.sfl[row * 192 + 96 + e];
        p.uw[(b * Tn + row) * 192 + e]      = f2bf(S.p2sl[row][0] * xm);
        p.uw[(b * Tn + row) * 192 + 96 + e] = f2bf(S.p2sl[row][1] * xm);
    }
    if (tid < 40) {
        int row = tid >> 1, c = tid & 1;
        long long idx = b * 880 + 840 + row * 2 + c;
        if (f) p.out1f[idx] = S.p2sl[row][c]; else p.out1[idx] = f2bf(S.p2sl[row][c]);
    }
}

// ------------- the fused kernel (plain launch + software grid barrier) -------------
__global__ __launch_bounds__(256, 1) void k_loop(Ptrs p) {
    const int bid = blockIdx.x;
    const int tid = threadIdx.x;
    const int f = p.flagp[0];
    const int gtid = bid * 256 + tid;
    unsigned gen = 0;

    __shared__ SMem sm;

    // phase 0: normalize small tensors + gather/pack (both depend only on inputs)
    norm_phase(p, gtid, f);
    #pragma unroll 1
    for (int i0 = gtid; i0 < 7421168; i0 += 65536) prep_one(p, i0, f);
    gbar(p.bar, bid, tid, ++gen);

    // recurrent loop: 3 phases per step
    #pragma unroll 1
    for (int t = 0; t < Tn; ++t) {
        gates_tile(p, t, bid, tid, sm.g);
        if (bid < 80) gates_tile(p, t, bid + 256, tid, sm.g);
        gbar(p.bar, bid, tid, ++gen);
        if (bid < 128) mlp1_tile(p, t, bid, tid, sm.m);
        gbar(p.bar, bid, tid, ++gen);
        rest_block(p, t, bid, tid, f, sm.r);
        gbar(p.bar, bid, tid, ++gen);
    }

    // post: sf GEMM (240 tiles) then per-batch q-chain
    if (bid < 240) sf_tile(p, bid, tid, sm.s);
    gbar(p.bar, bid, tid, ++gen);
    qchain_block(p, bid, tid, f, sm.q);
}

// ------------- final GEMM: C[v,(b,t)] = W2C[v,:]·uw[n,:], K=192, out [B][V][T] -------------
__global__ __launch_bounds__(256) void k_final(Ptrs p) {
    const int n0 = blockIdx.x * 64;   // 80 blocks
    const int v0 = blockIdx.y * 128;  // 79 blocks
    const int tid = threadIdx.x, lane = tid & 63, wv = tid >> 6;
    const int f = p.flagp[0];
    __shared__ u16 Wl[128 * 104];
    __shared__ u16 Ul[64 * 104];
    f32x4 acc[2][4] = {};
    const int m = lane & 15, q = lane >> 4;
    for (int kc = 0; kc < 2; ++kc) {
        const int kb = kc * 96;
        __syncthreads();
        for (int i = tid; i < 1536; i += 256) {
            int ri = i / 12, k8 = (i % 12) * 8;
            *(uint4*)&Wl[ri * 104 + k8] = *(const uint4*)&p.W2C[(v0 + ri) * 192 + kb + k8];
        }
        for (int i = tid; i < 768; i += 256) {
            int ri = i / 12, k8 = (i % 12) * 8;
            *(uint4*)&Ul[ri * 104 + k8] = *(const uint4*)&p.uw[(n0 + ri) * 192 + kb + k8];
        }
        __syncthreads();
        #pragma unroll
        for (int ks = 0; ks < 3; ++ks) {
            int ko = ks * 32 + q * 8;
            bf16x8 a0 = frag(&Wl[(wv * 32 + m) * 104 + ko]);
            bf16x8 a1 = frag(&Wl[(wv * 32 + 16 + m) * 104 + ko]);
            #pragma unroll
            for (int ni = 0; ni < 4; ++ni) {
                bf16x8 bb = frag(&Ul[(ni * 16 + m) * 104 + ko]);
                acc[0][ni] = mfma16(a0, bb, acc[0][ni]);
                acc[1][ni] = mfma16(a1, bb, acc[1][ni]);
            }
        }
    }
    #pragma unroll
    for (int ni = 0; ni < 4; ++ni) {
        int n = n0 + ni * 16 + m;
        int bb = n / 20, tt = n % 20;
        float s0 = p.p2sbuf[n * 2], s1 = p.p2sbuf[n * 2 + 1];
        size_t base = (size_t)bb * 200080 + tt;
        #pragma unroll
        for (int mi = 0; mi < 2; ++mi) {
            #pragma unroll
            for (int r = 0; r < 4; ++r) {
                int v = v0 + wv * 32 + mi * 16 + q * 4 + r;
                if (v < Vn) {
                    float val = acc[mi][ni][r] + s0 * bf2f(p.n_gl2b[v]) + s1 * bf2f(p.n_ll2b[v]);
                    size_t idx = base + (size_t)v * 20;
                    if (f) p.out0f[idx] = val; else p.out0[idx] = f2bf(val);
                }
            }
        }
    }
}

extern "C" void kernel_launch(void* const* d_in, const int* in_sizes, int n_in,
                              void* d_out, int out_size, void* d_ws, size_t ws_size,
                              hipStream_t stream) {
    Ptrs p;
    p.x    = (const int*)d_in[0];
    p.emb  = (const u16*)d_in[1];
    p.g_wi = (const u16*)d_in[2];  p.g_wh = (const u16*)d_in[3];
    p.g_bi = (const u16*)d_in[4];  p.g_bh = (const u16*)d_in[5];
    p.l_wi = (const u16*)d_in[6];  p.l_wh = (const u16*)d_in[7];
    p.l_bi = (const u16*)d_in[8];  p.l_bh = (const u16*)d_in[9];
    p.gl1_w = (const u16*)d_in[10]; p.gl1_b = (const u16*)d_in[11];
    p.ll1_w = (const u16*)d_in[12]; p.ll1_b = (const u16*)d_in[13];
    p.gl2_w = (const u16*)d_in[14]; p.gl2_b = (const u16*)d_in[15];
    p.ll2_w = (const u16*)d_in[16]; p.ll2_b = (const u16*)d_in[17];
    p.p1_w = (const u16*)d_in[18]; p.p1_b = (const u16*)d_in[19];
    p.p2_w = (const u16*)d_in[20]; p.p2_b = (const u16*)d_in[21];
    p.p3_w = (const u16*)d_in[22]; p.p3_b = (const u16*)d_in[23];
    p.p4_w = (const u16*)d_in[24]; p.p4_b = (const u16*)d_in[25];
    p.pe_w = (const u16*)d_in[26]; p.pe_b = (const u16*)d_in[27];
    p.q1_w = (const u16*)d_in[28]; p.q1_b = (const u16*)d_in[29];
    p.q2_w = (const u16*)d_in[30]; p.q2_b = (const u16*)d_in[31];
    p.q2e_w = (const u16*)d_in[32]; p.q2e_b = (const u16*)d_in[33];
    p.q3_w = (const u16*)d_in[34]; p.q3_b = (const u16*)d_in[35];
    p.q3e_w = (const u16*)d_in[36]; p.q3e_b = (const u16*)d_in[37];

    char* w = (char*)d_ws;
    auto carve = [&](size_t bytes) { char* r = w; w += (bytes + 255) & ~(size_t)255; return r; };
    p.bar    = (unsigned*)carve(32768);
    p.flagp  = (int*)carve(256);
    p.embs   = (u16*)carve((size_t)20 * 256 * 96 * 2);
    p.WgCat  = (u16*)carve((size_t)2 * 2680 * 768 * 2);
    p.P1W    = (u16*)carve((size_t)512 * 1440 * 2);
    p.W1C    = (u16*)carve((size_t)192 * 672 * 2);
    p.W2C    = (u16*)carve((size_t)10112 * 192 * 2);
    p.BSUM   = (float*)carve((size_t)2 * 2680 * 4);
    p.hs     = (u16*)carve((size_t)5120 * 672 * 2);
    p.hcat   = (u16*)carve((size_t)2 * 256 * 1344 * 2);
    p.uw     = (u16*)carve((size_t)5120 * 192 * 2);
    p.ghf    = (float*)carve((size_t)256 * 670 * 4);
    p.gcf    = (float*)carve((size_t)256 * 670 * 4);
    p.lhf    = (float*)carve((size_t)256 * 670 * 4);
    p.lc2    = (float*)carve((size_t)2 * 256 * 670 * 4);
    p.gcm    = (float*)carve((size_t)256 * 670 * 4);
    p.L1out  = (float*)carve((size_t)256 * 500 * 4);
    p.sf     = (float*)carve((size_t)5120 * 192 * 4);
    p.p2sbuf = (float*)carve((size_t)5120 * 2 * 4);
    p.n_p1b = (u16*)carve(500 * 2);   p.n_p2w = (u16*)carve(125000 * 2);
    p.n_p2b = (u16*)carve(250 * 2);   p.n_p3w = (u16*)carve(25000 * 2);
    p.n_p3b = (u16*)carve(100 * 2);   p.n_p4w = (u16*)carve(5000 * 2);
    p.n_p4b = (u16*)carve(50 * 2);    p.n_pew = (u16*)carve(100 * 2);
    p.n_peb = (u16*)carve(2 * 2);
    p.n_gl1b = (u16*)carve(96 * 2);   p.n_ll1b = (u16*)carve(96 * 2);
    p.n_gl2b = (u16*)carve(10004 * 2); p.n_ll2b = (u16*)carve(10004 * 2);
    p.n_q1w = (u16*)carve(14400 * 2); p.n_q1b = (u16*)carve(75 * 2);
    p.n_q2w = (u16*)carve(2250 * 2);  p.n_q2b = (u16*)carve(30 * 2);
    p.n_q2ew = (u16*)carve(60 * 2);   p.n_q2eb = (u16*)carve(2 * 2);
    p.n_q3w = (u16*)carve(300 * 2);   p.n_q3b = (u16*)carve(10 * 2);
    p.n_q3ew = (u16*)carve(20 * 2);   p.n_q3eb = (u16*)carve(2 * 2);
    p.out0 = (u16*)d_out;
    p.out1 = p.out0 + 51220480;
    p.out0f = (float*)d_out;
    p.out1f = p.out0f + 51220480;

    k_detect<<<1, 256, 0, stream>>>(p);
    k_loop<<<NBLK, 256, 0, stream>>>(p);
    k_final<<<dim3(80, 79), 256, 0, stream>>>(p);
}

// Round 4
// 1955.739 us; speedup vs baseline: 2.8878x; 2.8878x over previous
//
#include <hip/hip_runtime.h>

#define DI __device__ __forceinline__

typedef unsigned short u16;
typedef unsigned int u32;
typedef __bf16 bf16x8 __attribute__((ext_vector_type(8)));
typedef float f32x4 __attribute__((ext_vector_type(4)));
typedef u32 u32x4 __attribute__((ext_vector_type(4)));

// Model dims
static constexpr int B = 256, Tn = 20, En = 96, Hn = 670, Vn = 10004;
static constexpr int HP = 672;            // padded hidden
static constexpr int NBLK = 336;          // k_loop grid size (= gates tile count)
static constexpr int GT = NBLK * 256;     // grid threads

DI float bf2f(u16 u) { union { u32 i; float f; } v; v.i = ((u32)u) << 16; return v.f; }
DI u16 f2bf(float f) {
    u32 u = __float_as_uint(f);
    u32 r = (u + 0x7FFFu + ((u >> 16) & 1u)) >> 16;
    return (u16)r;
}
DI float sigm(float x) { return 1.f / (1.f + __expf(-x)); }
DI float tanha(float x) {
    x = fminf(fmaxf(x, -15.f), 15.f);
    float e = __expf(2.f * x);
    return (e - 1.f) / (e + 1.f);
}
DI bf16x8 frag(const u16* p) { return *(const bf16x8*)p; }
DI f32x4 mfma16(bf16x8 a, bf16x8 b, f32x4 c) {
    return __builtin_amdgcn_mfma_f32_16x16x32_bf16(a, b, c, 0, 0, 0);
}
// flag-aware element loads (f=1 -> source is float32, f=0 -> bf16)
DI u16 ldw(const u16* src, long long i, int f) {
    return f ? f2bf(((const float*)src)[i]) : src[i];
}
DI float ldf(const u16* src, long long i, int f) {
    return f ? ((const float*)src)[i] : bf2f(src[i]);
}

// ---- cache-bypassing (device-coherent, sc0 sc1 -> fabric) access helpers ----
DI u32x4 ldg16(const void* p) {
    u32x4 v;
    asm volatile("global_load_dwordx4 %0, %1, off sc0 sc1\n\ts_waitcnt vmcnt(0)"
                 : "=v"(v) : "v"(p));
    return v;
}
DI void ldg4f(const float* p0, const float* p1, const float* p2, const float* p3,
              float& a, float& b, float& c, float& d) {
    asm volatile("global_load_dword %0, %4, off sc0 sc1\n\t"
                 "global_load_dword %1, %5, off sc0 sc1\n\t"
                 "global_load_dword %2, %6, off sc0 sc1\n\t"
                 "global_load_dword %3, %7, off sc0 sc1\n\t"
                 "s_waitcnt vmcnt(0)"
                 : "=&v"(a), "=&v"(b), "=&v"(c), "=&v"(d)
                 : "v"(p0), "v"(p1), "v"(p2), "v"(p3));
}
DI u32 ldgu32(const u32* p) {
    u32 v;
    asm volatile("global_load_dword %0, %1, off sc0 sc1\n\ts_waitcnt vmcnt(0)"
                 : "=v"(v) : "v"(p));
    return v;
}
DI void stg32(float* p, float v) {
    asm volatile("global_store_dword %0, %1, off sc0 sc1" :: "v"(p), "v"(v) : "memory");
}
DI void stgu32(u32* p, u32 v) {
    asm volatile("global_store_dword %0, %1, off sc0 sc1" :: "v"(p), "v"(v) : "memory");
}
DI void stg16(u16* p, u16 v) {
    asm volatile("global_store_short %0, %1, off sc0 sc1" :: "v"(p), "v"((u32)v) : "memory");
}

struct Ptrs {
    const int* x;
    const u16 *emb, *g_wi, *g_wh, *g_bi, *g_bh, *l_wi, *l_wh, *l_bi, *l_bh;
    const u16 *gl1_w, *gl1_b, *ll1_w, *ll1_b, *gl2_w, *gl2_b, *ll2_w, *ll2_b;
    const u16 *p1_w, *p1_b, *p2_w, *p2_b, *p3_w, *p3_b, *p4_w, *p4_b, *pe_w, *pe_b;
    const u16 *q1_w, *q1_b, *q2_w, *q2_b, *q2e_w, *q2e_b, *q3_w, *q3_b, *q3e_w, *q3e_b;
    // scratch
    unsigned *bar; // [0]=broadcast flag; [32 + bid*16]=per-block arrival slots (64B spaced)
    int  *flagp;  // [0] = 1 if inputs are float32
    u16 *embs;    // [T][B][96] bf16
    u16 *WgCat;   // [2][2680][768] bf16 : [wi(96) | wh(670) | pad]
    u16 *P1W;     // [512][1472] bf16 (K padded with zeros)
    u16 *W1C;     // [192][672] bf16
    u16 *W2C;     // [10112][192] bf16 : [gl2_w | ll2_w]
    float *BSUM;  // [2][2680] f32 bias sums
    u16 *hs;      // [5120][672] bf16 (row n = b*20+t)
    u16 *hcat;    // [2][B][1344] bf16 double-buffered
    u16 *uw;      // [5120][192] bf16
    float *ghf, *gcf, *lhf, *lc2, *gcm;
    float *L1out; // [B][500]
    float *sf;    // [5120][192]
    float *p2sbuf;// [5120][2]
    // normalized bf16 copies of small tensors
    u16 *n_p1b, *n_p2w, *n_p2b, *n_p3w, *n_p3b, *n_p4w, *n_p4b, *n_pew, *n_peb;
    u16 *n_gl1b, *n_ll1b, *n_gl2b, *n_ll2b;
    u16 *n_q1w, *n_q1b, *n_q2w, *n_q2b, *n_q2ew, *n_q2eb, *n_q3w, *n_q3b, *n_q3ew, *n_q3eb;
    u16 *out0, *out1;
    float *out0f, *out1f;
};

// ---------------- software grid barrier ----------------
// Lite: no cache maintenance. All cross-block data moves via sc0/sc1 bypass ops which
// are coherent at the fabric; vmcnt(0) guarantees they are globally visible before the
// (bypassing) signal store. Heavy: adds __threadfence (wb+inv) for normally-cached data
// produced before the barrier (used once, after prep).
template<bool HEAVY>
DI void gbar(unsigned* bar, int bid, int tid, unsigned gen) {
    __syncthreads();                 // per-wave vmcnt(0): all stores complete
    if (tid == 0) {
        if (HEAVY) __threadfence();  // writeback dirty L2 so other XCDs can see prep data
        else asm volatile("s_waitcnt vmcnt(0)" ::: "memory");
        stgu32(&bar[32 + bid * 16], gen);
    }
    if (bid == 0) {
        for (int i = tid; i < NBLK; i += 256) {
            while ((int)(ldgu32(&bar[32 + i * 16]) - gen) < 0)
                __builtin_amdgcn_s_sleep(4);
        }
        __syncthreads();
        if (tid == 0) stgu32(&bar[0], gen);
    } else if (tid == 0) {
        while ((int)(ldgu32(&bar[0]) - gen) < 0)
            __builtin_amdgcn_s_sleep(8);
    }
    __syncthreads();
    if (HEAVY) {
        if (tid == 0) __threadfence();   // invalidate L1/L2 before cached reads
        __syncthreads();
    }
}

// ------------- detect input dtype + init barrier -------------
__global__ __launch_bounds__(256) void k_detect(Ptrs p) {
    int tid = threadIdx.x;
    for (int i = tid; i < 8192; i += 256) p.bar[i] = 0u;
    if (tid < 64) {
        u32 d = ((const u32*)p.g_bi)[tid];   // first 64 dwords of g_bi
        u16 lo = (u16)(d & 0xffffu);
        int e = (lo >> 7) & 0xff;             // bf16 exponent field of the LOW u16
        unsigned long long m = __ballot(e >= 127);   // |x|>=1 impossible for bf16 N(0,.05) data
        if (tid == 0) p.flagp[0] = (m != 0ull) ? 1 : 0;
    }
}

// ---------------- shared-memory phase overlays ----------------
struct SMg { u16 Al[32 * 72]; u16 Wl[128 * 72]; float bs[128]; };
struct SMm { u16 Al[32 * 72]; u16 Wl[32 * 72]; };
struct SMr { float l1[500]; float h2s[250]; float h3s[100]; float h4s[52]; float pr[4]; };
struct SMs { u16 Al[64 * 40]; u16 Wl[64 * 40]; };
struct SMq {
    float sfl[3840];
    float h1[20][80]; float h2[20][32]; float h3[20][12];
    float yv[20][2]; float zv[20][2]; float p1s[20][2]; float p2sl[20][2];
};
union alignas(16) SMem { SMg g; SMm m; SMr r; SMs s; SMq q; };

// ---------------- phase: normalize small tensors (grid-stride) ----------------
DI void norm_phase(const Ptrs& p, int gtid, int f) {
    const u16* srcs[23] = {p.p1_b, p.p2_w, p.p2_b, p.p3_w, p.p3_b, p.p4_w, p.p4_b,
                           p.pe_w, p.pe_b, p.gl1_b, p.ll1_b, p.gl2_b, p.ll2_b,
                           p.q1_w, p.q1_b, p.q2_w, p.q2_b, p.q2e_w, p.q2e_b,
                           p.q3_w, p.q3_b, p.q3e_w, p.q3e_b};
    u16* dsts[23] = {p.n_p1b, p.n_p2w, p.n_p2b, p.n_p3w, p.n_p3b, p.n_p4w, p.n_p4b,
                     p.n_pew, p.n_peb, p.n_gl1b, p.n_ll1b, p.n_gl2b, p.n_ll2b,
                     p.n_q1w, p.n_q1b, p.n_q2w, p.n_q2b, p.n_q2ew, p.n_q2eb,
                     p.n_q3w, p.n_q3b, p.n_q3ew, p.n_q3eb};
    const int ns[23] = {500, 125000, 250, 25000, 100, 5000, 50, 100, 2, 96, 96, 10004, 10004,
                        14400, 75, 2250, 30, 60, 2, 300, 10, 20, 2};
    for (int i0 = gtid; i0 < 193351; i0 += GT) {
        int i = i0;
        #pragma unroll 1
        for (int s = 0; s < 23; ++s) {
            if (i < ns[s]) { dsts[s][i] = ldw(srcs[s], i, f); break; }
            i -= ns[s];
        }
    }
}

// ---------------- phase: gather embeddings, pack/pad weights (grid-stride) ----------------
DI void prep_one(const Ptrs& p, int i, int f) {
    if (i < 491520) { // embs gather, elementwise
        int r = i / 96, j = i % 96;
        int t = r >> 8, b = r & 255;
        int idx = p.x[b * Tn + t];
        p.embs[r * 96 + j] = ldw(p.emb, (long long)idx * 96 + j, f);
        return;
    }
    i -= 491520;
    if (i < 2 * 2680 * 768) { // WgCat
        int z = i / (2680 * 768);
        int rem = i - z * (2680 * 768);
        int col = rem / 768, k = rem % 768;
        const u16* wi = z ? p.l_wi : p.g_wi;
        const u16* wh = z ? p.l_wh : p.g_wh;
        u16 v = 0;
        if (k < 96) v = ldw(wi, col * 96 + k, f);
        else { int j = k - 96; if (j < 670) v = ldw(wh, col * 670 + j, f); }
        p.WgCat[i] = v;
        return;
    }
    i -= 2 * 2680 * 768;
    if (i < 512 * 1472) { // P1W (K padded to 1472 with zeros)
        int col = i / 1472, k = i % 1472;
        u16 v = 0;
        if (col < 500) {
            if (k < 96) v = ldw(p.p1_w, col * 1436 + k, f);
            else if (k < 768) { int j = k - 96;  if (j < 670) v = ldw(p.p1_w, col * 1436 + 96 + j, f); }
            else              { int j = k - 768; if (j < 670) v = ldw(p.p1_w, col * 1436 + 766 + j, f); }
        }
        p.P1W[i] = v;
        return;
    }
    i -= 512 * 1472;
    if (i < 192 * 672) { // W1C
        int o = i / 672, h = i % 672;
        u16 v = 0;
        if (h < 670) v = (o < 96) ? ldw(p.gl1_w, o * 670 + h, f) : ldw(p.ll1_w, (o - 96) * 670 + h, f);
        p.W1C[i] = v;
        return;
    }
    i -= 192 * 672;
    if (i < 10112 * 192) { // W2C
        int v_ = i / 192, k = i % 192;
        u16 v = 0;
        if (v_ < Vn) v = (k < 96) ? ldw(p.gl2_w, v_ * 96 + k, f) : ldw(p.ll2_w, v_ * 96 + (k - 96), f);
        p.W2C[i] = v;
        return;
    }
    i -= 10112 * 192;
    if (i < 2 * 2680) { // BSUM
        int z = i / 2680, col = i % 2680;
        const u16* bi = z ? p.l_bi : p.g_bi;
        const u16* bh = z ? p.l_bh : p.g_bh;
        p.BSUM[i] = ldf(bi, col, f) + ldf(bh, col, f);
    }
}

// ------------- phase: fused gates GEMM + LSTM elementwise (one tile, BK=64) -------------
DI void gates_tile(const Ptrs& p, int t, int tau, int tid, SMg& S) {
    const int z = tau / 168;
    const int rem = tau - z * 168;
    const int jt = rem % 21, mt = rem / 21;
    const int row0 = mt * 32, j0 = jt * 32;
    const int lane = tid & 63, wv = tid >> 6;

    __syncthreads();
    if (tid < 128) {
        int gate = tid >> 5, jj = tid & 31, j = j0 + jj;
        S.bs[tid] = (j < Hn) ? p.BSUM[z * 2680 + gate * Hn + j] : 0.f;
    }
    const int cur = t & 1, prv = cur ^ 1;
    f32x4 acc[4] = {};
    const int mtw = wv & 1, jh = wv >> 1;

    for (int kc = 0; kc < 12; ++kc) {
        const int kb = kc * 64;
        __syncthreads();
        // weights first (normal cached loads, L2-hot across steps)
        #pragma unroll
        for (int it = 0; it < 4; ++it) {
            int idx = tid + it * 256;
            int ri = idx >> 3, k8 = (idx & 7) * 8;
            int gate = ri >> 5, jj = ri & 31, j = j0 + jj;
            u32x4 val = {0, 0, 0, 0};
            if (j < Hn) val = *(const u32x4*)&p.WgCat[(z * 2680 + gate * Hn + j) * 768 + kb + k8];
            *(u32x4*)&S.Wl[ri * 72 + k8] = val;
        }
        // activations (recurrent -> bypass)
        {
            int r = tid >> 3, k8 = (tid & 7) * 8, k = kb + k8;
            int b = row0 + r;
            u32x4 val = {0, 0, 0, 0};
            if (k < 96) val = *(const u32x4*)&p.embs[(t * 256 + b) * 96 + k];
            else if (t > 0) {
                int kk = k - 96;
                const u16* src = (z == 0) ? (p.hs + (b * Tn + (t - 1)) * HP + kk)
                                          : (p.hcat + prv * (B * 1344) + b * 1344 + 672 + kk);
                val = ldg16(src);
            }
            *(u32x4*)&S.Al[r * 72 + k8] = val;
        }
        __syncthreads();
        #pragma unroll
        for (int ks = 0; ks < 2; ++ks) {
            bf16x8 a = frag(&S.Al[(mtw * 16 + (lane & 15)) * 72 + ks * 32 + (lane >> 4) * 8]);
            #pragma unroll
            for (int g = 0; g < 4; ++g) {
                int nt = g * 2 + jh;
                bf16x8 bb = frag(&S.Wl[(nt * 16 + (lane & 15)) * 72 + ks * 32 + (lane >> 4) * 8]);
                acc[g] = mfma16(a, bb, acc[g]);
            }
        }
    }
    const int q = lane >> 4;
    const int jj = jh * 16 + (lane & 15);
    const int j = j0 + jj;
    const bool valid = (j < Hn);
    float cp0 = 0.f, cp1 = 0.f, cp2 = 0.f, cp3 = 0.f;
    const int b0 = row0 + mtw * 16 + q * 4;
    if (valid && t > 0) {
        const float* cb = (z == 0) ? (p.gcm + j) : (p.lc2 + prv * (B * Hn) + j);
        ldg4f(cb + (long long)(b0 + 0) * Hn, cb + (long long)(b0 + 1) * Hn,
              cb + (long long)(b0 + 2) * Hn, cb + (long long)(b0 + 3) * Hn,
              cp0, cp1, cp2, cp3);
    }
    float cps[4] = {cp0, cp1, cp2, cp3};
    #pragma unroll
    for (int r = 0; r < 4; ++r) {
        int b = b0 + r;
        float I = fminf(fmaxf(acc[0][r] + S.bs[jj], -30.f), 30.f);
        float F = fminf(fmaxf(acc[1][r] + S.bs[32 + jj], -30.f), 30.f);
        float G = fminf(fmaxf(acc[2][r] + S.bs[64 + jj], -30.f), 30.f);
        float O = fminf(fmaxf(acc[3][r] + S.bs[96 + jj], -30.f), 30.f);
        float c = sigm(F) * cps[r] + sigm(I) * tanha(G);
        float h = sigm(O) * tanha(c);
        if (z == 0) {
            if (valid) { stg32(&p.ghf[b * Hn + j], h); stg32(&p.gcf[b * Hn + j], c); }
            stg16(&p.hcat[cur * (B * 1344) + b * 1344 + j], valid ? f2bf(h) : (u16)0);
        } else {
            if (valid) { stg32(&p.lhf[b * Hn + j], h); stg32(&p.lc2[cur * (B * Hn) + b * Hn + j], c); }
            stg16(&p.hcat[cur * (B * 1344) + b * 1344 + 672 + j], valid ? f2bf(h) : (u16)0);
        }
    }
}

// ------------- phase: MLP layer 1 GEMM [256,1472]@[1472,512] (128 tiles 32x32, BK=64) -------------
DI void mlp1_tile(const Ptrs& p, int t, int bid, int tid, SMm& S) {
    const int col0 = (bid & 15) * 32;
    const int row0 = (bid >> 4) * 32;
    const int lane = tid & 63, wv = tid >> 6;
    const int cur = t & 1;
    f32x4 acc = {};
    const int mtw = wv & 1, nh = wv >> 1;
    for (int kc = 0; kc < 23; ++kc) {
        const int kb = kc * 64;
        __syncthreads();
        {
            int ri = tid >> 3, k8 = (tid & 7) * 8;
            *(u32x4*)&S.Wl[ri * 72 + k8] = *(const u32x4*)&p.P1W[(col0 + ri) * 1472 + kb + k8];
        }
        {
            int r = tid >> 3, k8 = (tid & 7) * 8, k = kb + k8;
            int b = row0 + r;
            u32x4 val = {0, 0, 0, 0};
            if (k < 96) val = *(const u32x4*)&p.embs[(t * 256 + b) * 96 + k];
            else if (k < 1440) val = ldg16(&p.hcat[cur * (B * 1344) + b * 1344 + (k - 96)]);
            *(u32x4*)&S.Al[r * 72 + k8] = val;
        }
        __syncthreads();
        #pragma unroll
        for (int ks = 0; ks < 2; ++ks) {
            bf16x8 a = frag(&S.Al[(mtw * 16 + (lane & 15)) * 72 + ks * 32 + (lane >> 4) * 8]);
            bf16x8 bb = frag(&S.Wl[(nh * 16 + (lane & 15)) * 72 + ks * 32 + (lane >> 4) * 8]);
            acc = mfma16(a, bb, acc);
        }
    }
    const int q = lane >> 4;
    int col = col0 + nh * 16 + (lane & 15);
    if (col < 500) {
        float bias = bf2f(p.n_p1b[col]);
        #pragma unroll
        for (int r = 0; r < 4; ++r) {
            int b = row0 + mtw * 16 + q * 4 + r;
            stg32(&p.L1out[b * 500 + col], fmaxf(acc[r] + bias, 0.f));
        }
    }
}

// ------------- phase: MLP layers 2..5, softmax, mix, write hs/out1 -------------
DI void rest_block(const Ptrs& p, int t, int b, int tid, int f, SMr& S) {
    if (tid < 125) {
        u32x4 v = ldg16(&p.L1out[b * 500 + tid * 4]);
        *(u32x4*)&S.l1[tid * 4] = v;
    }
    __syncthreads();
    if (tid < 250) {
        const u16* wr = p.n_p2w + tid * 500;
        float s = 0.f;
        for (int k = 0; k < 500; k += 4) {
            uint2 u = *(const uint2*)&wr[k];
            s += S.l1[k]     * bf2f((u16)(u.x & 0xffff));
            s += S.l1[k + 1] * bf2f((u16)(u.x >> 16));
            s += S.l1[k + 2] * bf2f((u16)(u.y & 0xffff));
            s += S.l1[k + 3] * bf2f((u16)(u.y >> 16));
        }
        S.h2s[tid] = fmaxf(s + bf2f(p.n_p2b[tid]), 0.f);
    }
    __syncthreads();
    if (tid < 100) {
        const u16* wr = p.n_p3w + tid * 250;
        float s = 0.f;
        for (int k = 0; k < 250; k += 2) {
            u32 u = *(const u32*)&wr[k];
            s += S.h2s[k]     * bf2f((u16)(u & 0xffff));
            s += S.h2s[k + 1] * bf2f((u16)(u >> 16));
        }
        S.h3s[tid] = fmaxf(s + bf2f(p.n_p3b[tid]), 0.f);
    }
    __syncthreads();
    if (tid < 50) {
        const u16* wr = p.n_p4w + tid * 100;
        float s = 0.f;
        for (int k = 0; k < 100; k += 4) {
            uint2 u = *(const uint2*)&wr[k];
            s += S.h3s[k]     * bf2f((u16)(u.x & 0xffff));
            s += S.h3s[k + 1] * bf2f((u16)(u.x >> 16));
            s += S.h3s[k + 2] * bf2f((u16)(u.y & 0xffff));
            s += S.h3s[k + 3] * bf2f((u16)(u.y >> 16));
        }
        S.h4s[tid] = fmaxf(s + bf2f(p.n_p4b[tid]), 0.f);
    }
    __syncthreads();
    if (tid == 0) {
        float e0 = bf2f(p.n_peb[0]), e1 = bf2f(p.n_peb[1]);
        for (int k = 0; k < 50; ++k) {
            e0 += S.h4s[k] * bf2f(p.n_pew[k]);
            e1 += S.h4s[k] * bf2f(p.n_pew[50 + k]);
        }
        float m = fmaxf(e0, e1);
        float a0 = __expf(e0 - m), a1 = __expf(e1 - m);
        float inv = 1.f / (a0 + a1);
        S.pr[0] = a0 * inv; S.pr[1] = a1 * inv;
    }
    __syncthreads();
    float p0 = S.pr[0], p1 = S.pr[1];
    const int cur = t & 1;
    for (int j = tid; j < HP; j += 256) {
        u16 hv = 0;
        if (j < Hn) {
            float lh, gh, lc, gc;
            ldg4f(&p.lhf[b * Hn + j], &p.ghf[b * Hn + j],
                  &p.lc2[cur * (B * Hn) + b * Hn + j], &p.gcf[b * Hn + j], lh, gh, lc, gc);
            float gm = p0 * lh + p1 * gh;
            float cm = p0 * lc + p1 * gc;
            stg32(&p.gcm[b * Hn + j], cm);
            hv = f2bf(gm);
        }
        stg16(&p.hs[(b * Tn + t) * HP + j], hv);
    }
    if (tid < 40) {
        long long idx = b * 880 + t * 40 + tid;
        float v = (tid & 1) ? p1 : p0;
        if (f) p.out1f[idx] = v; else p.out1[idx] = f2bf(v);
    }
}

// ------------- phase: sf = hs @ [gl1;ll1]^T + bias  ([5120,672]@[672,192]) -------------
DI void sf_tile(const Ptrs& p, int tau, int tid, SMs& S) {
    const int col0 = (tau % 3) * 64;
    const int row0 = (tau / 3) * 64;
    const int lane = tid & 63, wv = tid >> 6;
    f32x4 acc[4] = {};
    for (int kc = 0; kc < 21; ++kc) {
        const int kb = kc * 32;
        __syncthreads();
        {
            int r = tid >> 2, k8 = (tid & 3) * 8;
            *(u32x4*)&S.Wl[r * 40 + k8] = *(const u32x4*)&p.W1C[(col0 + r) * HP + kb + k8];
            *(u32x4*)&S.Al[r * 40 + k8] = ldg16(&p.hs[(row0 + r) * HP + kb + k8]);
        }
        __syncthreads();
        bf16x8 a = frag(&S.Al[(wv * 16 + (lane & 15)) * 40 + (lane >> 4) * 8]);
        #pragma unroll
        for (int nt = 0; nt < 4; ++nt) {
            bf16x8 bb = frag(&S.Wl[(nt * 16 + (lane & 15)) * 40 + (lane >> 4) * 8]);
            acc[nt] = mfma16(a, bb, acc[nt]);
        }
    }
    const int q = lane >> 4;
    #pragma unroll
    for (int nt = 0; nt < 4; ++nt) {
        int col = col0 + nt * 16 + (lane & 15);
        float bias = bf2f(col < 96 ? p.n_gl1b[col] : p.n_ll1b[col - 96]);
        #pragma unroll
        for (int r = 0; r < 4; ++r) {
            int row = row0 + wv * 16 + q * 4 + r;
            stg32(&p.sf[row * 192 + col], acc[nt][r] + bias);
        }
    }
}

// ------------- phase: per-batch q-chain, softmaxes, u/w, out1 rows 20/21 -------------
DI void qchain_block(const Ptrs& p, int b, int tid, int f, SMq& S) {
    for (int i = tid; i < 960; i += 256) {
        u32x4 v = ldg16(&p.sf[b * 3840 + i * 4]);
        *(u32x4*)&S.sfl[i * 4] = v;
    }
    __syncthreads();
    for (int u = tid; u < 1500; u += 256) {
        int row = u / 75, o = u % 75;
        const u16* wr = p.n_q1w + o * 192;
        const float* sr = &S.sfl[row * 192];
        float s = bf2f(p.n_q1b[o]);
        for (int k = 0; k < 192; k += 4) {
            uint2 w = *(const uint2*)&wr[k];
            s += sr[k]     * bf2f((u16)(w.x & 0xffff));
            s += sr[k + 1] * bf2f((u16)(w.x >> 16));
            s += sr[k + 2] * bf2f((u16)(w.y & 0xffff));
            s += sr[k + 3] * bf2f((u16)(w.y >> 16));
        }
        S.h1[row][o] = fmaxf(s, 0.f);
    }
    __syncthreads();
    for (int u = tid; u < 600; u += 256) {
        int row = u / 30, o = u % 30;
        const u16* wr = p.n_q2w + o * 75;
        float s = bf2f(p.n_q2b[o]);
        for (int k = 0; k < 75; ++k) s += S.h1[row][k] * bf2f(wr[k]);
        S.h2[row][o] = fmaxf(s, 0.f);
    }
    __syncthreads();
    if (tid < 40) {
        int row = tid >> 1, o = tid & 1;
        const u16* wr = p.n_q2ew + o * 30;
        float s = bf2f(p.n_q2eb[o]);
        for (int k = 0; k < 30; ++k) s += S.h2[row][k] * bf2f(wr[k]);
        S.yv[row][o] = fmaxf(s, 0.f);
    } else if (tid >= 56 && tid < 256) {
        int u = tid - 56;  // 200 units
        int row = u / 10, o = u % 10;
        const u16* wr = p.n_q3w + o * 30;
        float s = bf2f(p.n_q3b[o]);
        for (int k = 0; k < 30; ++k) s += S.h2[row][k] * bf2f(wr[k]);
        S.h3[row][o] = fmaxf(s, 0.f);
    }
    __syncthreads();
    if (tid < 40) {
        int row = tid >> 1, o = tid & 1;
        const u16* wr = p.n_q3ew + o * 10;
        float s = bf2f(p.n_q3eb[o]);
        for (int k = 0; k < 10; ++k) s += S.h3[row][k] * bf2f(wr[k]);
        S.zv[row][o] = fmaxf(s, 0.f);
    } else if (tid >= 64 && tid < 84) {
        int row = tid - 64;
        float m = fmaxf(S.yv[row][0], S.yv[row][1]);
        float a0 = __expf(S.yv[row][0] - m), a1 = __expf(S.yv[row][1] - m);
        float inv = 1.f / (a0 + a1);
        S.p1s[row][0] = a0 * inv; S.p1s[row][1] = a1 * inv;
    }
    __syncthreads();
    if (tid < 20) {
        float m = fmaxf(S.zv[tid][0], S.zv[tid][1]);
        float a0 = __expf(S.zv[tid][0] - m), a1 = __expf(S.zv[tid][1] - m);
        float inv = 1.f / (a0 + a1);
        S.p2sl[tid][0] = a0 * inv; S.p2sl[tid][1] = a1 * inv;
        p.p2sbuf[(b * Tn + tid) * 2]     = a0 * inv;
        p.p2sbuf[(b * Tn + tid) * 2 + 1] = a1 * inv;
    } else if (tid >= 64 && tid < 104) {
        int row = (tid - 64) >> 1, c = (tid - 64) & 1;
        long long idx = b * 880 + 800 + row * 2 + c;
        if (f) p.out1f[idx] = S.p1s[row][c]; else p.out1[idx] = f2bf(S.p1s[row][c]);
    }
    __syncthreads();
    for (int u = tid; u < 1920; u += 256) {
        int row = u / 96, e = u % 96;
        float xm = S.p1s[row][0] * S.sfl[row * 192 + e] + S.p1s[row][1] * S.sfl[row * 192 + 96 + e];
        p.uw[(b * Tn + row) * 192 + e]      = f2bf(S.p2sl[row][0] * xm);
        p.uw[(b * Tn + row) * 192 + 96 + e] = f2bf(S.p2sl[row][1] * xm);
    }
    if (tid < 40) {
        int row = tid >> 1, c = tid & 1;
        long long idx = b * 880 + 840 + row * 2 + c;
        if (f) p.out1f[idx] = S.p2sl[row][c]; else p.out1[idx] = f2bf(S.p2sl[row][c]);
    }
}

// ------------- the fused kernel -------------
__global__ __launch_bounds__(256, 2) void k_loop(Ptrs p) {
    const int bid = blockIdx.x;
    const int tid = threadIdx.x;
    const int f = p.flagp[0];
    const int gtid = bid * 256 + tid;
    unsigned gen = 0;

    __shared__ SMem sm;

    // phase 0: normalize small tensors + gather/pack
    norm_phase(p, gtid, f);
    #pragma unroll 1
    for (int i0 = gtid; i0 < 7437552; i0 += GT) prep_one(p, i0, f);
    gbar<true>(p.bar, bid, tid, ++gen);   // the only heavy barrier: publish cached weights

    // recurrent loop: 3 phases per step, lite barriers only
    #pragma unroll 1
    for (int t = 0; t < Tn; ++t) {
        gates_tile(p, t, bid, tid, sm.g);
        gbar<false>(p.bar, bid, tid, ++gen);
        if (bid < 128) mlp1_tile(p, t, bid, tid, sm.m);
        gbar<false>(p.bar, bid, tid, ++gen);
        if (bid < 256) rest_block(p, t, bid, tid, f, sm.r);
        gbar<false>(p.bar, bid, tid, ++gen);
    }

    // post: sf GEMM (240 tiles, bypass hs reads) then per-batch q-chain (bypass sf reads)
    if (bid < 240) sf_tile(p, bid, tid, sm.s);
    gbar<false>(p.bar, bid, tid, ++gen);
    if (bid < 256) qchain_block(p, bid, tid, f, sm.q);
}

// ------------- final GEMM: C[v,(b,t)] = W2C[v,:]·uw[n,:], K=192, out [B][V][T] -------------
__global__ __launch_bounds__(256) void k_final(Ptrs p) {
    const int n0 = blockIdx.x * 64;   // 80 blocks
    const int v0 = blockIdx.y * 128;  // 79 blocks
    const int tid = threadIdx.x, lane = tid & 63, wv = tid >> 6;
    const int f = p.flagp[0];
    __shared__ u16 Wl[128 * 104];
    __shared__ u16 Ul[64 * 104];
    f32x4 acc[2][4] = {};
    const int m = lane & 15, q = lane >> 4;
    for (int kc = 0; kc < 2; ++kc) {
        const int kb = kc * 96;
        __syncthreads();
        for (int i = tid; i < 1536; i += 256) {
            int ri = i / 12, k8 = (i % 12) * 8;
            *(uint4*)&Wl[ri * 104 + k8] = *(const uint4*)&p.W2C[(v0 + ri) * 192 + kb + k8];
        }
        for (int i = tid; i < 768; i += 256) {
            int ri = i / 12, k8 = (i % 12) * 8;
            *(uint4*)&Ul[ri * 104 + k8] = *(const uint4*)&p.uw[(n0 + ri) * 192 + kb + k8];
        }
        __syncthreads();
        #pragma unroll
        for (int ks = 0; ks < 3; ++ks) {
            int ko = ks * 32 + q * 8;
            bf16x8 a0 = frag(&Wl[(wv * 32 + m) * 104 + ko]);
            bf16x8 a1 = frag(&Wl[(wv * 32 + 16 + m) * 104 + ko]);
            #pragma unroll
            for (int ni = 0; ni < 4; ++ni) {
                bf16x8 bb = frag(&Ul[(ni * 16 + m) * 104 + ko]);
                acc[0][ni] = mfma16(a0, bb, acc[0][ni]);
                acc[1][ni] = mfma16(a1, bb, acc[1][ni]);
            }
        }
    }
    #pragma unroll
    for (int ni = 0; ni < 4; ++ni) {
        int n = n0 + ni * 16 + m;
        int bb = n / 20, tt = n % 20;
        float s0 = p.p2sbuf[n * 2], s1 = p.p2sbuf[n * 2 + 1];
        size_t base = (size_t)bb * 200080 + tt;
        #pragma unroll
        for (int mi = 0; mi < 2; ++mi) {
            #pragma unroll
            for (int r = 0; r < 4; ++r) {
                int v = v0 + wv * 32 + mi * 16 + q * 4 + r;
                if (v < Vn) {
                    float val = acc[mi][ni][r] + s0 * bf2f(p.n_gl2b[v]) + s1 * bf2f(p.n_ll2b[v]);
                    size_t idx = base + (size_t)v * 20;
                    if (f) p.out0f[idx] = val; else p.out0[idx] = f2bf(val);
                }
            }
        }
    }
}

extern "C" void kernel_launch(void* const* d_in, const int* in_sizes, int n_in,
                              void* d_out, int out_size, void* d_ws, size_t ws_size,
                              hipStream_t stream) {
    Ptrs p;
    p.x    = (const int*)d_in[0];
    p.emb  = (const u16*)d_in[1];
    p.g_wi = (const u16*)d_in[2];  p.g_wh = (const u16*)d_in[3];
    p.g_bi = (const u16*)d_in[4];  p.g_bh = (const u16*)d_in[5];
    p.l_wi = (const u16*)d_in[6];  p.l_wh = (const u16*)d_in[7];
    p.l_bi = (const u16*)d_in[8];  p.l_bh = (const u16*)d_in[9];
    p.gl1_w = (const u16*)d_in[10]; p.gl1_b = (const u16*)d_in[11];
    p.ll1_w = (const u16*)d_in[12]; p.ll1_b = (const u16*)d_in[13];
    p.gl2_w = (const u16*)d_in[14]; p.gl2_b = (const u16*)d_in[15];
    p.ll2_w = (const u16*)d_in[16]; p.ll2_b = (const u16*)d_in[17];
    p.p1_w = (const u16*)d_in[18]; p.p1_b = (const u16*)d_in[19];
    p.p2_w = (const u16*)d_in[20]; p.p2_b = (const u16*)d_in[21];
    p.p3_w = (const u16*)d_in[22]; p.p3_b = (const u16*)d_in[23];
    p.p4_w = (const u16*)d_in[24]; p.p4_b = (const u16*)d_in[25];
    p.pe_w = (const u16*)d_in[26]; p.pe_b = (const u16*)d_in[27];
    p.q1_w = (const u16*)d_in[28]; p.q1_b = (const u16*)d_in[29];
    p.q2_w = (const u16*)d_in[30]; p.q2_b = (const u16*)d_in[31];
    p.q2e_w = (const u16*)d_in[32]; p.q2e_b = (const u16*)d_in[33];
    p.q3_w = (const u16*)d_in[34]; p.q3_b = (const u16*)d_in[35];
    p.q3e_w = (const u16*)d_in[36]; p.q3e_b = (const u16*)d_in[37];

    char* w = (char*)d_ws;
    auto carve = [&](size_t bytes) { char* r = w; w += (bytes + 255) & ~(size_t)255; return r; };
    p.bar    = (unsigned*)carve(32768);
    p.flagp  = (int*)carve(256);
    p.embs   = (u16*)carve((size_t)20 * 256 * 96 * 2);
    p.WgCat  = (u16*)carve((size_t)2 * 2680 * 768 * 2);
    p.P1W    = (u16*)carve((size_t)512 * 1472 * 2);
    p.W1C    = (u16*)carve((size_t)192 * 672 * 2);
    p.W2C    = (u16*)carve((size_t)10112 * 192 * 2);
    p.BSUM   = (float*)carve((size_t)2 * 2680 * 4);
    p.hs     = (u16*)carve((size_t)5120 * 672 * 2);
    p.hcat   = (u16*)carve((size_t)2 * 256 * 1344 * 2);
    p.uw     = (u16*)carve((size_t)5120 * 192 * 2);
    p.ghf    = (float*)carve((size_t)256 * 670 * 4);
    p.gcf    = (float*)carve((size_t)256 * 670 * 4);
    p.lhf    = (float*)carve((size_t)256 * 670 * 4);
    p.lc2    = (float*)carve((size_t)2 * 256 * 670 * 4);
    p.gcm    = (float*)carve((size_t)256 * 670 * 4);
    p.L1out  = (float*)carve((size_t)256 * 500 * 4);
    p.sf     = (float*)carve((size_t)5120 * 192 * 4);
    p.p2sbuf = (float*)carve((size_t)5120 * 2 * 4);
    p.n_p1b = (u16*)carve(500 * 2);   p.n_p2w = (u16*)carve(125000 * 2);
    p.n_p2b = (u16*)carve(250 * 2);   p.n_p3w = (u16*)carve(25000 * 2);
    p.n_p3b = (u16*)carve(100 * 2);   p.n_p4w = (u16*)carve(5000 * 2);
    p.n_p4b = (u16*)carve(50 * 2);    p.n_pew = (u16*)carve(100 * 2);
    p.n_peb = (u16*)carve(2 * 2);
    p.n_gl1b = (u16*)carve(96 * 2);   p.n_ll1b = (u16*)carve(96 * 2);
    p.n_gl2b = (u16*)carve(10004 * 2); p.n_ll2b = (u16*)carve(10004 * 2);
    p.n_q1w = (u16*)carve(14400 * 2); p.n_q1b = (u16*)carve(75 * 2);
    p.n_q2w = (u16*)carve(2250 * 2);  p.n_q2b = (u16*)carve(30 * 2);
    p.n_q2ew = (u16*)carve(60 * 2);   p.n_q2eb = (u16*)carve(2 * 2);
    p.n_q3w = (u16*)carve(300 * 2);   p.n_q3b = (u16*)carve(10 * 2);
    p.n_q3ew = (u16*)carve(20 * 2);   p.n_q3eb = (u16*)carve(2 * 2);
    p.out0 = (u16*)d_out;
    p.out1 = p.out0 + 51220480;
    p.out0f = (float*)d_out;
    p.out1f = p.out0f + 51220480;

    k_detect<<<1, 256, 0, stream>>>(p);
    k_loop<<<NBLK, 256, 0, stream>>>(p);
    k_final<<<dim3(80, 79), 256, 0, stream>>>(p);
}

// Round 5
// 1839.911 us; speedup vs baseline: 3.0696x; 1.0630x over previous
//
#include <hip/hip_runtime.h>

#define DI __device__ __forceinline__

typedef unsigned short u16;
typedef unsigned int u32;
typedef __bf16 bf16x8 __attribute__((ext_vector_type(8)));
typedef float f32x4 __attribute__((ext_vector_type(4)));
typedef u32 u32x4 __attribute__((ext_vector_type(4)));

// Model dims
static constexpr int B = 256, Tn = 20, En = 96, Hn = 670, Vn = 10004;
static constexpr int HP = 672;            // padded hidden
static constexpr int NBLK = 384;          // k_loop grid size (gates: 336 valid + 48 idle)
static constexpr int GT = NBLK * 256;     // grid threads

DI float bf2f(u16 u) { union { u32 i; float f; } v; v.i = ((u32)u) << 16; return v.f; }
DI u16 f2bf(float f) {
    u32 u = __float_as_uint(f);
    u32 r = (u + 0x7FFFu + ((u >> 16) & 1u)) >> 16;
    return (u16)r;
}
DI float sigm(float x) { return 1.f / (1.f + __expf(-x)); }
DI float tanha(float x) {
    x = fminf(fmaxf(x, -15.f), 15.f);
    float e = __expf(2.f * x);
    return (e - 1.f) / (e + 1.f);
}
DI bf16x8 frag(const u16* p) { return *(const bf16x8*)p; }
DI f32x4 mfma16(bf16x8 a, bf16x8 b, f32x4 c) {
    return __builtin_amdgcn_mfma_f32_16x16x32_bf16(a, b, c, 0, 0, 0);
}
// flag-aware element loads (f=1 -> source is float32, f=0 -> bf16)
DI u16 ldw(const u16* src, long long i, int f) {
    return f ? f2bf(((const float*)src)[i]) : src[i];
}
DI float ldf(const u16* src, long long i, int f) {
    return f ? ((const float*)src)[i] : bf2f(src[i]);
}

// ---- cache-bypassing (device-coherent, sc0 sc1 -> fabric) access helpers ----
// Used for STORES of cross-block data (no local L2 copy -> no staleness anywhere),
// and for the few same-address-reused reads (ghf/gcf/lhf/L1out).
DI u32x4 ldg16(const void* p) {
    u32x4 v;
    asm volatile("global_load_dwordx4 %0, %1, off sc0 sc1\n\ts_waitcnt vmcnt(0)"
                 : "=v"(v) : "v"(p));
    return v;
}
DI void ldg4f(const float* p0, const float* p1, const float* p2, const float* p3,
              float& a, float& b, float& c, float& d) {
    asm volatile("global_load_dword %0, %4, off sc0 sc1\n\t"
                 "global_load_dword %1, %5, off sc0 sc1\n\t"
                 "global_load_dword %2, %6, off sc0 sc1\n\t"
                 "global_load_dword %3, %7, off sc0 sc1\n\t"
                 "s_waitcnt vmcnt(0)"
                 : "=&v"(a), "=&v"(b), "=&v"(c), "=&v"(d)
                 : "v"(p0), "v"(p1), "v"(p2), "v"(p3));
}
DI u32 ldgu32(const u32* p) {
    u32 v;
    asm volatile("global_load_dword %0, %1, off sc0 sc1\n\ts_waitcnt vmcnt(0)"
                 : "=v"(v) : "v"(p));
    return v;
}
DI void stg32(float* p, float v) {
    asm volatile("global_store_dword %0, %1, off sc0 sc1" :: "v"(p), "v"(v) : "memory");
}
DI void stgu32(u32* p, u32 v) {
    asm volatile("global_store_dword %0, %1, off sc0 sc1" :: "v"(p), "v"(v) : "memory");
}
DI void stg16(u16* p, u16 v) {
    asm volatile("global_store_short %0, %1, off sc0 sc1" :: "v"(p), "v"((u32)v) : "memory");
}

struct Ptrs {
    const int* x;
    const u16 *emb, *g_wi, *g_wh, *g_bi, *g_bh, *l_wi, *l_wh, *l_bi, *l_bh;
    const u16 *gl1_w, *gl1_b, *ll1_w, *ll1_b, *gl2_w, *gl2_b, *ll2_w, *ll2_b;
    const u16 *p1_w, *p1_b, *p2_w, *p2_b, *p3_w, *p3_b, *p4_w, *p4_b, *pe_w, *pe_b;
    const u16 *q1_w, *q1_b, *q2_w, *q2_b, *q2e_w, *q2e_b, *q3_w, *q3_b, *q3e_w, *q3e_b;
    // scratch
    unsigned *bar; // [0]=broadcast flag; [32 + bid*16]=per-block arrival slots (64B spaced)
    int  *flagp;  // [0] = 1 if inputs are float32
    u16 *embs;    // [T][B][96] bf16
    u16 *WgCat;   // [2][2680][768] bf16 : [wi(96) | wh(670) | pad]
    u16 *P1W;     // [512][1472] bf16 (K padded with zeros)
    u16 *W1C;     // [192][672] bf16
    u16 *W2C;     // [10112][192] bf16 : [gl2_w | ll2_w]
    float *BSUM;  // [2][2680] f32 bias sums
    u16 *hs;      // [T][B][672] bf16  (t-major: planes are write-once, line-aligned)
    u16 *hcat;    // [T][B][1344] bf16 (time-indexed -> write-once)
    u16 *uw;      // [5120][192] bf16
    float *ghf, *gcf, *lhf;   // [B][670] f32, same-step only (bypass both ways)
    float *lc2;   // [T][B][670] f32 (time-indexed -> write-once)
    float *gcm;   // [T][B][670] f32 (time-indexed -> write-once)
    float *L1out; // [B][500]
    float *sf;    // [5120][192]
    float *p2sbuf;// [5120][2]
    // normalized bf16 copies of small tensors
    u16 *n_p1b, *n_p2w, *n_p2b, *n_p3w, *n_p3b, *n_p4w, *n_p4b, *n_pew, *n_peb;
    u16 *n_gl1b, *n_ll1b, *n_gl2b, *n_ll2b;
    u16 *n_q1w, *n_q1b, *n_q2w, *n_q2b, *n_q2ew, *n_q2eb, *n_q3w, *n_q3b, *n_q3ew, *n_q3eb;
    u16 *out0, *out1;
    float *out0f, *out1f;
};

// ---------------- software grid barrier ----------------
// Lite: no cache maintenance. Cross-block data is written via sc0/sc1 bypass stores
// (coherent at fabric) and read via CACHED loads -- safe because every such tensor is
// write-once-per-launch (time-indexed planes) and all stale lines from previous launches
// are invalidated by the heavy barrier's trailing __threadfence on every XCD.
template<bool HEAVY>
DI void gbar(unsigned* bar, int bid, int tid, unsigned gen) {
    __syncthreads();                 // per-wave vmcnt(0): all stores complete
    if (tid == 0) {
        if (HEAVY) __threadfence();  // writeback dirty L2 so other XCDs can see prep data
        else asm volatile("s_waitcnt vmcnt(0)" ::: "memory");
        stgu32(&bar[32 + bid * 16], gen);
    }
    if (bid == 0) {
        for (int i = tid; i < NBLK; i += 256) {
            while ((int)(ldgu32(&bar[32 + i * 16]) - gen) < 0)
                __builtin_amdgcn_s_sleep(4);
        }
        __syncthreads();
        if (tid == 0) stgu32(&bar[0], gen);
    } else if (tid == 0) {
        while ((int)(ldgu32(&bar[0]) - gen) < 0)
            __builtin_amdgcn_s_sleep(8);
    }
    __syncthreads();
    if (HEAVY) {
        if (tid == 0) __threadfence();   // invalidate local L2 (also clears prev-launch lines)
        __syncthreads();
    }
}

// ------------- detect input dtype + init barrier -------------
__global__ __launch_bounds__(256) void k_detect(Ptrs p) {
    int tid = threadIdx.x;
    for (int i = tid; i < 8192; i += 256) p.bar[i] = 0u;
    if (tid < 64) {
        u32 d = ((const u32*)p.g_bi)[tid];   // first 64 dwords of g_bi
        u16 lo = (u16)(d & 0xffffu);
        int e = (lo >> 7) & 0xff;             // bf16 exponent field of the LOW u16
        unsigned long long m = __ballot(e >= 127);   // |x|>=1 impossible for bf16 N(0,.05) data
        if (tid == 0) p.flagp[0] = (m != 0ull) ? 1 : 0;
    }
}

// ---------------- shared-memory phase overlays ----------------
struct SMg { u16 Al[32 * 72]; u16 Wl[128 * 72]; float bs[128]; };
struct SMm { u16 Al[32 * 72]; u16 Wl[32 * 72]; };
struct SMr { float l1[500]; float h2s[250]; float h3s[100]; float h4s[52]; float pr[4]; };
struct SMs { u16 Al[64 * 40]; u16 Wl[64 * 40]; };
struct SMq {
    float sfl[3840];
    float h1[20][80]; float h2[20][32]; float h3[20][12];
    float yv[20][2]; float zv[20][2]; float p1s[20][2]; float p2sl[20][2];
};
union alignas(16) SMem { SMg g; SMm m; SMr r; SMs s; SMq q; };

// ---------------- phase: normalize small tensors (grid-stride) ----------------
DI void norm_phase(const Ptrs& p, int gtid, int f) {
    const u16* srcs[23] = {p.p1_b, p.p2_w, p.p2_b, p.p3_w, p.p3_b, p.p4_w, p.p4_b,
                           p.pe_w, p.pe_b, p.gl1_b, p.ll1_b, p.gl2_b, p.ll2_b,
                           p.q1_w, p.q1_b, p.q2_w, p.q2_b, p.q2e_w, p.q2e_b,
                           p.q3_w, p.q3_b, p.q3e_w, p.q3e_b};
    u16* dsts[23] = {p.n_p1b, p.n_p2w, p.n_p2b, p.n_p3w, p.n_p3b, p.n_p4w, p.n_p4b,
                     p.n_pew, p.n_peb, p.n_gl1b, p.n_ll1b, p.n_gl2b, p.n_ll2b,
                     p.n_q1w, p.n_q1b, p.n_q2w, p.n_q2b, p.n_q2ew, p.n_q2eb,
                     p.n_q3w, p.n_q3b, p.n_q3ew, p.n_q3eb};
    const int ns[23] = {500, 125000, 250, 25000, 100, 5000, 50, 100, 2, 96, 96, 10004, 10004,
                        14400, 75, 2250, 30, 60, 2, 300, 10, 20, 2};
    for (int i0 = gtid; i0 < 193351; i0 += GT) {
        int i = i0;
        #pragma unroll 1
        for (int s = 0; s < 23; ++s) {
            if (i < ns[s]) { dsts[s][i] = ldw(srcs[s], i, f); break; }
            i -= ns[s];
        }
    }
}

// ---------------- phase: gather embeddings, pack/pad weights (grid-stride) ----------------
DI void prep_one(const Ptrs& p, int i, int f) {
    if (i < 491520) { // embs gather, elementwise
        int r = i / 96, j = i % 96;
        int t = r >> 8, b = r & 255;
        int idx = p.x[b * Tn + t];
        p.embs[r * 96 + j] = ldw(p.emb, (long long)idx * 96 + j, f);
        return;
    }
    i -= 491520;
    if (i < 2 * 2680 * 768) { // WgCat
        int z = i / (2680 * 768);
        int rem = i - z * (2680 * 768);
        int col = rem / 768, k = rem % 768;
        const u16* wi = z ? p.l_wi : p.g_wi;
        const u16* wh = z ? p.l_wh : p.g_wh;
        u16 v = 0;
        if (k < 96) v = ldw(wi, col * 96 + k, f);
        else { int j = k - 96; if (j < 670) v = ldw(wh, col * 670 + j, f); }
        p.WgCat[i] = v;
        return;
    }
    i -= 2 * 2680 * 768;
    if (i < 512 * 1472) { // P1W (K padded to 1472 with zeros)
        int col = i / 1472, k = i % 1472;
        u16 v = 0;
        if (col < 500) {
            if (k < 96) v = ldw(p.p1_w, col * 1436 + k, f);
            else if (k < 768) { int j = k - 96;  if (j < 670) v = ldw(p.p1_w, col * 1436 + 96 + j, f); }
            else              { int j = k - 768; if (j < 670) v = ldw(p.p1_w, col * 1436 + 766 + j, f); }
        }
        p.P1W[i] = v;
        return;
    }
    i -= 512 * 1472;
    if (i < 192 * 672) { // W1C
        int o = i / 672, h = i % 672;
        u16 v = 0;
        if (h < 670) v = (o < 96) ? ldw(p.gl1_w, o * 670 + h, f) : ldw(p.ll1_w, (o - 96) * 670 + h, f);
        p.W1C[i] = v;
        return;
    }
    i -= 192 * 672;
    if (i < 10112 * 192) { // W2C
        int v_ = i / 192, k = i % 192;
        u16 v = 0;
        if (v_ < Vn) v = (k < 96) ? ldw(p.gl2_w, v_ * 96 + k, f) : ldw(p.ll2_w, v_ * 96 + (k - 96), f);
        p.W2C[i] = v;
        return;
    }
    i -= 10112 * 192;
    if (i < 2 * 2680) { // BSUM
        int z = i / 2680, col = i % 2680;
        const u16* bi = z ? p.l_bi : p.g_bi;
        const u16* bh = z ? p.l_bh : p.g_bh;
        p.BSUM[i] = ldf(bi, col, f) + ldf(bh, col, f);
    }
}

// ------------- phase: fused gates GEMM + LSTM elementwise (one tile, BK=64) -------------
// Activations (hs/hcat, write-once planes) read CACHED; state stored via bypass.
DI void gates_tile(const Ptrs& p, int t, int z, int jt, int mt, int tid, SMg& S) {
    const int row0 = mt * 32, j0 = jt * 32;
    const int lane = tid & 63, wv = tid >> 6;

    __syncthreads();
    if (tid < 128) {
        int gate = tid >> 5, jj = tid & 31, j = j0 + jj;
        S.bs[tid] = (j < Hn) ? p.BSUM[z * 2680 + gate * Hn + j] : 0.f;
    }
    f32x4 acc[4] = {};
    const int mtw = wv & 1, jh = wv >> 1;

    for (int kc = 0; kc < 12; ++kc) {
        const int kb = kc * 64;
        __syncthreads();
        #pragma unroll
        for (int it = 0; it < 4; ++it) {
            int idx = tid + it * 256;
            int ri = idx >> 3, k8 = (idx & 7) * 8;
            int gate = ri >> 5, jj = ri & 31, j = j0 + jj;
            u32x4 val = {0, 0, 0, 0};
            if (j < Hn) val = *(const u32x4*)&p.WgCat[(z * 2680 + gate * Hn + j) * 768 + kb + k8];
            *(u32x4*)&S.Wl[ri * 72 + k8] = val;
        }
        {
            int r = tid >> 3, k8 = (tid & 7) * 8, k = kb + k8;
            int b = row0 + r;
            u32x4 val = {0, 0, 0, 0};
            if (k < 96) val = *(const u32x4*)&p.embs[(t * 256 + b) * 96 + k];
            else if (t > 0) {
                int kk = k - 96;
                const u16* src = (z == 0) ? (p.hs + ((t - 1) * B + b) * HP + kk)
                                          : (p.hcat + (t - 1) * (B * 1344) + b * 1344 + 672 + kk);
                val = *(const u32x4*)src;
            }
            *(u32x4*)&S.Al[r * 72 + k8] = val;
        }
        __syncthreads();
        #pragma unroll
        for (int ks = 0; ks < 2; ++ks) {
            bf16x8 a = frag(&S.Al[(mtw * 16 + (lane & 15)) * 72 + ks * 32 + (lane >> 4) * 8]);
            #pragma unroll
            for (int g = 0; g < 4; ++g) {
                int nt = g * 2 + jh;
                bf16x8 bb = frag(&S.Wl[(nt * 16 + (lane & 15)) * 72 + ks * 32 + (lane >> 4) * 8]);
                acc[g] = mfma16(a, bb, acc[g]);
            }
        }
    }
    const int q = lane >> 4;
    const int jj = jh * 16 + (lane & 15);
    const int j = j0 + jj;
    const bool valid = (j < Hn);
    const int b0 = row0 + mtw * 16 + q * 4;
    float cps[4] = {0.f, 0.f, 0.f, 0.f};
    if (valid && t > 0) {
        const float* cb = ((z == 0) ? p.gcm : p.lc2) + (t - 1) * (B * Hn) + j;
        #pragma unroll
        for (int r = 0; r < 4; ++r) cps[r] = cb[(b0 + r) * Hn];   // cached, write-once plane
    }
    #pragma unroll
    for (int r = 0; r < 4; ++r) {
        int b = b0 + r;
        float I = fminf(fmaxf(acc[0][r] + S.bs[jj], -30.f), 30.f);
        float F = fminf(fmaxf(acc[1][r] + S.bs[32 + jj], -30.f), 30.f);
        float G = fminf(fmaxf(acc[2][r] + S.bs[64 + jj], -30.f), 30.f);
        float O = fminf(fmaxf(acc[3][r] + S.bs[96 + jj], -30.f), 30.f);
        float c = sigm(F) * cps[r] + sigm(I) * tanha(G);
        float h = sigm(O) * tanha(c);
        if (z == 0) {
            if (valid) { stg32(&p.ghf[b * Hn + j], h); stg32(&p.gcf[b * Hn + j], c); }
            stg16(&p.hcat[t * (B * 1344) + b * 1344 + j], valid ? f2bf(h) : (u16)0);
        } else {
            if (valid) { stg32(&p.lhf[b * Hn + j], h); stg32(&p.lc2[t * (B * Hn) + b * Hn + j], c); }
            stg16(&p.hcat[t * (B * 1344) + b * 1344 + 672 + j], valid ? f2bf(h) : (u16)0);
        }
    }
}

// ------------- phase: MLP layer 1 GEMM [256,1472]@[1472,512] (128 tiles 32x32, BK=64) -------------
DI void mlp1_tile(const Ptrs& p, int t, int bid, int tid, SMm& S) {
    const int col0 = (bid & 15) * 32;
    const int row0 = (bid >> 4) * 32;
    const int lane = tid & 63, wv = tid >> 6;
    f32x4 acc = {};
    const int mtw = wv & 1, nh = wv >> 1;
    for (int kc = 0; kc < 23; ++kc) {
        const int kb = kc * 64;
        __syncthreads();
        {
            int ri = tid >> 3, k8 = (tid & 7) * 8;
            *(u32x4*)&S.Wl[ri * 72 + k8] = *(const u32x4*)&p.P1W[(col0 + ri) * 1472 + kb + k8];
        }
        {
            int r = tid >> 3, k8 = (tid & 7) * 8, k = kb + k8;
            int b = row0 + r;
            u32x4 val = {0, 0, 0, 0};
            if (k < 96) val = *(const u32x4*)&p.embs[(t * 256 + b) * 96 + k];
            else if (k < 1440) val = *(const u32x4*)&p.hcat[t * (B * 1344) + b * 1344 + (k - 96)];
            *(u32x4*)&S.Al[r * 72 + k8] = val;
        }
        __syncthreads();
        #pragma unroll
        for (int ks = 0; ks < 2; ++ks) {
            bf16x8 a = frag(&S.Al[(mtw * 16 + (lane & 15)) * 72 + ks * 32 + (lane >> 4) * 8]);
            bf16x8 bb = frag(&S.Wl[(nh * 16 + (lane & 15)) * 72 + ks * 32 + (lane >> 4) * 8]);
            acc = mfma16(a, bb, acc);
        }
    }
    const int q = lane >> 4;
    int col = col0 + nh * 16 + (lane & 15);
    if (col < 500) {
        float bias = bf2f(p.n_p1b[col]);
        #pragma unroll
        for (int r = 0; r < 4; ++r) {
            int b = row0 + mtw * 16 + q * 4 + r;
            stg32(&p.L1out[b * 500 + col], fmaxf(acc[r] + bias, 0.f));
        }
    }
}

// ------------- phase: MLP layers 2..5, softmax, mix, write hs/out1 -------------
DI void rest_block(const Ptrs& p, int t, int b, int tid, int f, SMr& S) {
    if (tid < 125) {
        u32x4 v = ldg16(&p.L1out[b * 500 + tid * 4]);
        *(u32x4*)&S.l1[tid * 4] = v;
    }
    __syncthreads();
    if (tid < 250) {
        const u16* wr = p.n_p2w + tid * 500;
        float s = 0.f;
        for (int k = 0; k < 500; k += 4) {
            uint2 u = *(const uint2*)&wr[k];
            s += S.l1[k]     * bf2f((u16)(u.x & 0xffff));
            s += S.l1[k + 1] * bf2f((u16)(u.x >> 16));
            s += S.l1[k + 2] * bf2f((u16)(u.y & 0xffff));
            s += S.l1[k + 3] * bf2f((u16)(u.y >> 16));
        }
        S.h2s[tid] = fmaxf(s + bf2f(p.n_p2b[tid]), 0.f);
    }
    __syncthreads();
    if (tid < 100) {
        const u16* wr = p.n_p3w + tid * 250;
        float s = 0.f;
        for (int k = 0; k < 250; k += 2) {
            u32 u = *(const u32*)&wr[k];
            s += S.h2s[k]     * bf2f((u16)(u & 0xffff));
            s += S.h2s[k + 1] * bf2f((u16)(u >> 16));
        }
        S.h3s[tid] = fmaxf(s + bf2f(p.n_p3b[tid]), 0.f);
    }
    __syncthreads();
    if (tid < 50) {
        const u16* wr = p.n_p4w + tid * 100;
        float s = 0.f;
        for (int k = 0; k < 100; k += 4) {
            uint2 u = *(const uint2*)&wr[k];
            s += S.h3s[k]     * bf2f((u16)(u.x & 0xffff));
            s += S.h3s[k + 1] * bf2f((u16)(u.x >> 16));
            s += S.h3s[k + 2] * bf2f((u16)(u.y & 0xffff));
            s += S.h3s[k + 3] * bf2f((u16)(u.y >> 16));
        }
        S.h4s[tid] = fmaxf(s + bf2f(p.n_p4b[tid]), 0.f);
    }
    __syncthreads();
    if (tid == 0) {
        float e0 = bf2f(p.n_peb[0]), e1 = bf2f(p.n_peb[1]);
        for (int k = 0; k < 50; ++k) {
            e0 += S.h4s[k] * bf2f(p.n_pew[k]);
            e1 += S.h4s[k] * bf2f(p.n_pew[50 + k]);
        }
        float m = fmaxf(e0, e1);
        float a0 = __expf(e0 - m), a1 = __expf(e1 - m);
        float inv = 1.f / (a0 + a1);
        S.pr[0] = a0 * inv; S.pr[1] = a1 * inv;
    }
    __syncthreads();
    float p0 = S.pr[0], p1 = S.pr[1];
    for (int j = tid; j < HP; j += 256) {
        u16 hv = 0;
        if (j < Hn) {
            float lh, gh, lc, gc;
            ldg4f(&p.lhf[b * Hn + j], &p.ghf[b * Hn + j],
                  &p.lc2[t * (B * Hn) + b * Hn + j], &p.gcf[b * Hn + j], lh, gh, lc, gc);
            float gm = p0 * lh + p1 * gh;
            float cm = p0 * lc + p1 * gc;
            stg32(&p.gcm[t * (B * Hn) + b * Hn + j], cm);
            hv = f2bf(gm);
        }
        stg16(&p.hs[(t * B + b) * HP + j], hv);
    }
    if (tid < 40) {
        long long idx = b * 880 + t * 40 + tid;
        float v = (tid & 1) ? p1 : p0;
        if (f) p.out1f[idx] = v; else p.out1[idx] = f2bf(v);
    }
}

// ------------- phase: sf = hs @ [gl1;ll1]^T + bias  ([5120,672]@[672,192]) -------------
DI void sf_tile(const Ptrs& p, int tau, int tid, SMs& S) {
    const int col0 = (tau % 3) * 64;
    const int row0 = (tau / 3) * 64;
    const int lane = tid & 63, wv = tid >> 6;
    // output row n = b*20+t; hs stored t-major: plane t, row b
    const int n = row0 + (tid >> 2);
    const u16* arow = p.hs + ((n % Tn) * B + (n / Tn)) * HP;
    f32x4 acc[4] = {};
    for (int kc = 0; kc < 21; ++kc) {
        const int kb = kc * 32;
        __syncthreads();
        {
            int r = tid >> 2, k8 = (tid & 3) * 8;
            *(u32x4*)&S.Wl[r * 40 + k8] = *(const u32x4*)&p.W1C[(col0 + r) * HP + kb + k8];
            *(u32x4*)&S.Al[r * 40 + k8] = *(const u32x4*)&arow[kb + k8];
        }
        __syncthreads();
        bf16x8 a = frag(&S.Al[(wv * 16 + (lane & 15)) * 40 + (lane >> 4) * 8]);
        #pragma unroll
        for (int nt = 0; nt < 4; ++nt) {
            bf16x8 bb = frag(&S.Wl[(nt * 16 + (lane & 15)) * 40 + (lane >> 4) * 8]);
            acc[nt] = mfma16(a, bb, acc[nt]);
        }
    }
    const int q = lane >> 4;
    #pragma unroll
    for (int nt = 0; nt < 4; ++nt) {
        int col = col0 + nt * 16 + (lane & 15);
        float bias = bf2f(col < 96 ? p.n_gl1b[col] : p.n_ll1b[col - 96]);
        #pragma unroll
        for (int r = 0; r < 4; ++r) {
            int row = row0 + wv * 16 + q * 4 + r;
            stg32(&p.sf[row * 192 + col], acc[nt][r] + bias);
        }
    }
}

// ------------- phase: per-batch q-chain, softmaxes, u/w, out1 rows 20/21 -------------
DI void qchain_block(const Ptrs& p, int b, int tid, int f, SMq& S) {
    for (int i = tid; i < 960; i += 256)
        *(float4*)&S.sfl[i * 4] = *(const float4*)&p.sf[b * 3840 + i * 4];  // cached: sf write-once
    __syncthreads();
    for (int u = tid; u < 1500; u += 256) {
        int row = u / 75, o = u % 75;
        const u16* wr = p.n_q1w + o * 192;
        const float* sr = &S.sfl[row * 192];
        float s = bf2f(p.n_q1b[o]);
        for (int k = 0; k < 192; k += 4) {
            uint2 w = *(const uint2*)&wr[k];
            s += sr[k]     * bf2f((u16)(w.x & 0xffff));
            s += sr[k + 1] * bf2f((u16)(w.x >> 16));
            s += sr[k + 2] * bf2f((u16)(w.y & 0xffff));
            s += sr[k + 3] * bf2f((u16)(w.y >> 16));
        }
        S.h1[row][o] = fmaxf(s, 0.f);
    }
    __syncthreads();
    for (int u = tid; u < 600; u += 256) {
        int row = u / 30, o = u % 30;
        const u16* wr = p.n_q2w + o * 75;
        float s = bf2f(p.n_q2b[o]);
        for (int k = 0; k < 75; ++k) s += S.h1[row][k] * bf2f(wr[k]);
        S.h2[row][o] = fmaxf(s, 0.f);
    }
    __syncthreads();
    if (tid < 40) {
        int row = tid >> 1, o = tid & 1;
        const u16* wr = p.n_q2ew + o * 30;
        float s = bf2f(p.n_q2eb[o]);
        for (int k = 0; k < 30; ++k) s += S.h2[row][k] * bf2f(wr[k]);
        S.yv[row][o] = fmaxf(s, 0.f);
    } else if (tid >= 56 && tid < 256) {
        int u = tid - 56;  // 200 units
        int row = u / 10, o = u % 10;
        const u16* wr = p.n_q3w + o * 30;
        float s = bf2f(p.n_q3b[o]);
        for (int k = 0; k < 30; ++k) s += S.h2[row][k] * bf2f(wr[k]);
        S.h3[row][o] = fmaxf(s, 0.f);
    }
    __syncthreads();
    if (tid < 40) {
        int row = tid >> 1, o = tid & 1;
        const u16* wr = p.n_q3ew + o * 10;
        float s = bf2f(p.n_q3eb[o]);
        for (int k = 0; k < 10; ++k) s += S.h3[row][k] * bf2f(wr[k]);
        S.zv[row][o] = fmaxf(s, 0.f);
    } else if (tid >= 64 && tid < 84) {
        int row = tid - 64;
        float m = fmaxf(S.yv[row][0], S.yv[row][1]);
        float a0 = __expf(S.yv[row][0] - m), a1 = __expf(S.yv[row][1] - m);
        float inv = 1.f / (a0 + a1);
        S.p1s[row][0] = a0 * inv; S.p1s[row][1] = a1 * inv;
    }
    __syncthreads();
    if (tid < 20) {
        float m = fmaxf(S.zv[tid][0], S.zv[tid][1]);
        float a0 = __expf(S.zv[tid][0] - m), a1 = __expf(S.zv[tid][1] - m);
        float inv = 1.f / (a0 + a1);
        S.p2sl[tid][0] = a0 * inv; S.p2sl[tid][1] = a1 * inv;
        p.p2sbuf[(b * Tn + tid) * 2]     = a0 * inv;
        p.p2sbuf[(b * Tn + tid) * 2 + 1] = a1 * inv;
    } else if (tid >= 64 && tid < 104) {
        int row = (tid - 64) >> 1, c = (tid - 64) & 1;
        long long idx = b * 880 + 800 + row * 2 + c;
        if (f) p.out1f[idx] = S.p1s[row][c]; else p.out1[idx] = f2bf(S.p1s[row][c]);
    }
    __syncthreads();
    for (int u = tid; u < 1920; u += 256) {
        int row = u / 96, e = u % 96;
        float xm = S.p1s[row][0] * S.sfl[row * 192 + e] + S.p1s[row][1] * S.sfl[row * 192 + 96 + e];
        p.uw[(b * Tn + row) * 192 + e]      = f2bf(S.p2sl[row][0] * xm);
        p.uw[(b * Tn + row) * 192 + 96 + e] = f2bf(S.p2sl[row][1] * xm);
    }
    if (tid < 40) {
        int row = tid >> 1, c = tid & 1;
        long long idx = b * 880 + 840 + row * 2 + c;
        if (f) p.out1f[idx] = S.p2sl[row][c]; else p.out1[idx] = f2bf(S.p2sl[row][c]);
    }
}

// ------------- the fused kernel -------------
__global__ __launch_bounds__(256, 2) void k_loop(Ptrs p) {
    const int bid = blockIdx.x;
    const int tid = threadIdx.x;
    const int f = p.flagp[0];
    const int gtid = bid * 256 + tid;
    unsigned gen = 0;

    __shared__ SMem sm;

    // phase 0: normalize small tensors + gather/pack
    norm_phase(p, gtid, f);
    #pragma unroll 1
    for (int i0 = gtid; i0 < 7437552; i0 += GT) prep_one(p, i0, f);
    gbar<true>(p.bar, bid, tid, ++gen);   // heavy: publish cached prep + invalidate stale L2 lines

    // XCD-aware gates mapping: all 8 mt-tiles of a (z,jt) pair land on one XCD
    // (bid%8 = XCD); z split by XCD group; per-XCD weight set ~1.15 MB -> L2-resident.
    const int gx = bid & 7, gg = bid >> 3;
    const int gz = gx >> 2, gjt = (gx & 3) * 6 + (gg >> 3), gmt = gg & 7;
    const bool gvalid = (gjt < 21);

    // recurrent loop: 3 phases per step, lite barriers only
    #pragma unroll 1
    for (int t = 0; t < Tn; ++t) {
        if (gvalid) gates_tile(p, t, gz, gjt, gmt, tid, sm.g);
        gbar<false>(p.bar, bid, tid, ++gen);
        if (bid < 128) mlp1_tile(p, t, bid, tid, sm.m);
        gbar<false>(p.bar, bid, tid, ++gen);
        if (bid < 256) rest_block(p, t, bid, tid, f, sm.r);
        gbar<false>(p.bar, bid, tid, ++gen);
    }

    // post: sf GEMM (240 tiles) then per-batch q-chain
    if (bid < 240) sf_tile(p, bid, tid, sm.s);
    gbar<false>(p.bar, bid, tid, ++gen);
    if (bid < 256) qchain_block(p, bid, tid, f, sm.q);
}

// ------------- final GEMM: C[v,(b,t)] = W2C[v,:]·uw[n,:], K=192, out [B][V][T] -------------
__global__ __launch_bounds__(256) void k_final(Ptrs p) {
    const int n0 = blockIdx.x * 64;   // 80 blocks
    const int v0 = blockIdx.y * 128;  // 79 blocks
    const int tid = threadIdx.x, lane = tid & 63, wv = tid >> 6;
    const int f = p.flagp[0];
    __shared__ u16 Wl[128 * 104];
    __shared__ u16 Ul[64 * 104];
    f32x4 acc[2][4] = {};
    const int m = lane & 15, q = lane >> 4;
    for (int kc = 0; kc < 2; ++kc) {
        const int kb = kc * 96;
        __syncthreads();
        for (int i = tid; i < 1536; i += 256) {
            int ri = i / 12, k8 = (i % 12) * 8;
            *(uint4*)&Wl[ri * 104 + k8] = *(const uint4*)&p.W2C[(v0 + ri) * 192 + kb + k8];
        }
        for (int i = tid; i < 768; i += 256) {
            int ri = i / 12, k8 = (i % 12) * 8;
            *(uint4*)&Ul[ri * 104 + k8] = *(const uint4*)&p.uw[(n0 + ri) * 192 + kb + k8];
        }
        __syncthreads();
        #pragma unroll
        for (int ks = 0; ks < 3; ++ks) {
            int ko = ks * 32 + q * 8;
            bf16x8 a0 = frag(&Wl[(wv * 32 + m) * 104 + ko]);
            bf16x8 a1 = frag(&Wl[(wv * 32 + 16 + m) * 104 + ko]);
            #pragma unroll
            for (int ni = 0; ni < 4; ++ni) {
                bf16x8 bb = frag(&Ul[(ni * 16 + m) * 104 + ko]);
                acc[0][ni] = mfma16(a0, bb, acc[0][ni]);
                acc[1][ni] = mfma16(a1, bb, acc[1][ni]);
            }
        }
    }
    #pragma unroll
    for (int ni = 0; ni < 4; ++ni) {
        int n = n0 + ni * 16 + m;
        int bb = n / 20, tt = n % 20;
        float s0 = p.p2sbuf[n * 2], s1 = p.p2sbuf[n * 2 + 1];
        size_t base = (size_t)bb * 200080 + tt;
        #pragma unroll
        for (int mi = 0; mi < 2; ++mi) {
            #pragma unroll
            for (int r = 0; r < 4; ++r) {
                int v = v0 + wv * 32 + mi * 16 + q * 4 + r;
                if (v < Vn) {
                    float val = acc[mi][ni][r] + s0 * bf2f(p.n_gl2b[v]) + s1 * bf2f(p.n_ll2b[v]);
                    size_t idx = base + (size_t)v * 20;
                    if (f) p.out0f[idx] = val; else p.out0[idx] = f2bf(val);
                }
            }
        }
    }
}

extern "C" void kernel_launch(void* const* d_in, const int* in_sizes, int n_in,
                              void* d_out, int out_size, void* d_ws, size_t ws_size,
                              hipStream_t stream) {
    Ptrs p;
    p.x    = (const int*)d_in[0];
    p.emb  = (const u16*)d_in[1];
    p.g_wi = (const u16*)d_in[2];  p.g_wh = (const u16*)d_in[3];
    p.g_bi = (const u16*)d_in[4];  p.g_bh = (const u16*)d_in[5];
    p.l_wi = (const u16*)d_in[6];  p.l_wh = (const u16*)d_in[7];
    p.l_bi = (const u16*)d_in[8];  p.l_bh = (const u16*)d_in[9];
    p.gl1_w = (const u16*)d_in[10]; p.gl1_b = (const u16*)d_in[11];
    p.ll1_w = (const u16*)d_in[12]; p.ll1_b = (const u16*)d_in[13];
    p.gl2_w = (const u16*)d_in[14]; p.gl2_b = (const u16*)d_in[15];
    p.ll2_w = (const u16*)d_in[16]; p.ll2_b = (const u16*)d_in[17];
    p.p1_w = (const u16*)d_in[18]; p.p1_b = (const u16*)d_in[19];
    p.p2_w = (const u16*)d_in[20]; p.p2_b = (const u16*)d_in[21];
    p.p3_w = (const u16*)d_in[22]; p.p3_b = (const u16*)d_in[23];
    p.p4_w = (const u16*)d_in[24]; p.p4_b = (const u16*)d_in[25];
    p.pe_w = (const u16*)d_in[26]; p.pe_b = (const u16*)d_in[27];
    p.q1_w = (const u16*)d_in[28]; p.q1_b = (const u16*)d_in[29];
    p.q2_w = (const u16*)d_in[30]; p.q2_b = (const u16*)d_in[31];
    p.q2e_w = (const u16*)d_in[32]; p.q2e_b = (const u16*)d_in[33];
    p.q3_w = (const u16*)d_in[34]; p.q3_b = (const u16*)d_in[35];
    p.q3e_w = (const u16*)d_in[36]; p.q3e_b = (const u16*)d_in[37];

    char* w = (char*)d_ws;
    auto carve = [&](size_t bytes) { char* r = w; w += (bytes + 255) & ~(size_t)255; return r; };
    p.bar    = (unsigned*)carve(32768);
    p.flagp  = (int*)carve(256);
    p.embs   = (u16*)carve((size_t)20 * 256 * 96 * 2);
    p.WgCat  = (u16*)carve((size_t)2 * 2680 * 768 * 2);
    p.P1W    = (u16*)carve((size_t)512 * 1472 * 2);
    p.W1C    = (u16*)carve((size_t)192 * 672 * 2);
    p.W2C    = (u16*)carve((size_t)10112 * 192 * 2);
    p.BSUM   = (float*)carve((size_t)2 * 2680 * 4);
    p.hs     = (u16*)carve((size_t)20 * 256 * 672 * 2);
    p.hcat   = (u16*)carve((size_t)20 * 256 * 1344 * 2);
    p.uw     = (u16*)carve((size_t)5120 * 192 * 2);
    p.ghf    = (float*)carve((size_t)256 * 670 * 4);
    p.gcf    = (float*)carve((size_t)256 * 670 * 4);
    p.lhf    = (float*)carve((size_t)256 * 670 * 4);
    p.lc2    = (float*)carve((size_t)20 * 256 * 670 * 4);
    p.gcm    = (float*)carve((size_t)20 * 256 * 670 * 4);
    p.L1out  = (float*)carve((size_t)256 * 500 * 4);
    p.sf     = (float*)carve((size_t)5120 * 192 * 4);
    p.p2sbuf = (float*)carve((size_t)5120 * 2 * 4);
    p.n_p1b = (u16*)carve(500 * 2);   p.n_p2w = (u16*)carve(125000 * 2);
    p.n_p2b = (u16*)carve(250 * 2);   p.n_p3w = (u16*)carve(25000 * 2);
    p.n_p3b = (u16*)carve(100 * 2);   p.n_p4w = (u16*)carve(5000 * 2);
    p.n_p4b = (u16*)carve(50 * 2);    p.n_pew = (u16*)carve(100 * 2);
    p.n_peb = (u16*)carve(2 * 2);
    p.n_gl1b = (u16*)carve(96 * 2);   p.n_ll1b = (u16*)carve(96 * 2);
    p.n_gl2b = (u16*)carve(10004 * 2); p.n_ll2b = (u16*)carve(10004 * 2);
    p.n_q1w = (u16*)carve(14400 * 2); p.n_q1b = (u16*)carve(75 * 2);
    p.n_q2w = (u16*)carve(2250 * 2);  p.n_q2b = (u16*)carve(30 * 2);
    p.n_q2ew = (u16*)carve(60 * 2);   p.n_q2eb = (u16*)carve(2 * 2);
    p.n_q3w = (u16*)carve(300 * 2);   p.n_q3b = (u16*)carve(10 * 2);
    p.n_q3ew = (u16*)carve(20 * 2);   p.n_q3eb = (u16*)carve(2 * 2);
    p.out0 = (u16*)d_out;
    p.out1 = p.out0 + 51220480;
    p.out0f = (float*)d_out;
    p.out1f = p.out0f + 51220480;

    k_detect<<<1, 256, 0, stream>>>(p);
    k_loop<<<NBLK, 256, 0, stream>>>(p);
    k_final<<<dim3(80, 79), 256, 0, stream>>>(p);
}

// Round 6
// 1801.662 us; speedup vs baseline: 3.1348x; 1.0212x over previous
//
#include <hip/hip_runtime.h>

#define DI __device__ __forceinline__

typedef unsigned short u16;
typedef unsigned int u32;
typedef __bf16 bf16x8 __attribute__((ext_vector_type(8)));
typedef float f32x4 __attribute__((ext_vector_type(4)));
typedef u32 u32x4 __attribute__((ext_vector_type(4)));

// Model dims
static constexpr int B = 256, Tn = 20, En = 96, Hn = 670, Vn = 10004;
static constexpr int HP = 672;            // padded hidden
static constexpr int NBLK = 384;          // k_loop grid size (gates: 336 valid + 48 idle)
static constexpr int GT = NBLK * 256;     // grid threads

DI float bf2f(u16 u) { union { u32 i; float f; } v; v.i = ((u32)u) << 16; return v.f; }
DI u16 f2bf(float f) {
    u32 u = __float_as_uint(f);
    u32 r = (u + 0x7FFFu + ((u >> 16) & 1u)) >> 16;
    return (u16)r;
}
DI float sigm(float x) { return 1.f / (1.f + __expf(-x)); }
DI float tanha(float x) {
    x = fminf(fmaxf(x, -15.f), 15.f);
    float e = __expf(2.f * x);
    return (e - 1.f) / (e + 1.f);
}
DI bf16x8 frag(const u16* p) { return *(const bf16x8*)p; }
DI f32x4 mfma16(bf16x8 a, bf16x8 b, f32x4 c) {
    return __builtin_amdgcn_mfma_f32_16x16x32_bf16(a, b, c, 0, 0, 0);
}
// flag-aware element loads (f=1 -> source is float32, f=0 -> bf16)
DI u16 ldw(const u16* src, long long i, int f) {
    return f ? f2bf(((const float*)src)[i]) : src[i];
}
DI float ldf(const u16* src, long long i, int f) {
    return f ? ((const float*)src)[i] : bf2f(src[i]);
}

// ---- cache-bypassing (device-coherent, sc0 sc1 -> fabric) access helpers ----
DI u32x4 ldg16(const void* p) {
    u32x4 v;
    asm volatile("global_load_dwordx4 %0, %1, off sc0 sc1\n\ts_waitcnt vmcnt(0)"
                 : "=v"(v) : "v"(p));
    return v;
}
DI void ldg4f(const float* p0, const float* p1, const float* p2, const float* p3,
              float& a, float& b, float& c, float& d) {
    asm volatile("global_load_dword %0, %4, off sc0 sc1\n\t"
                 "global_load_dword %1, %5, off sc0 sc1\n\t"
                 "global_load_dword %2, %6, off sc0 sc1\n\t"
                 "global_load_dword %3, %7, off sc0 sc1\n\t"
                 "s_waitcnt vmcnt(0)"
                 : "=&v"(a), "=&v"(b), "=&v"(c), "=&v"(d)
                 : "v"(p0), "v"(p1), "v"(p2), "v"(p3));
}
DI u32 ldgu32(const u32* p) {
    u32 v;
    asm volatile("global_load_dword %0, %1, off sc0 sc1\n\ts_waitcnt vmcnt(0)"
                 : "=v"(v) : "v"(p));
    return v;
}
DI void stg32(float* p, float v) {
    asm volatile("global_store_dword %0, %1, off sc0 sc1" :: "v"(p), "v"(v) : "memory");
}
DI void stgu32(u32* p, u32 v) {
    asm volatile("global_store_dword %0, %1, off sc0 sc1" :: "v"(p), "v"(v) : "memory");
}
DI void stg16(u16* p, u16 v) {
    asm volatile("global_store_short %0, %1, off sc0 sc1" :: "v"(p), "v"((u32)v) : "memory");
}

struct Ptrs {
    const int* x;
    const u16 *emb, *g_wi, *g_wh, *g_bi, *g_bh, *l_wi, *l_wh, *l_bi, *l_bh;
    const u16 *gl1_w, *gl1_b, *ll1_w, *ll1_b, *gl2_w, *gl2_b, *ll2_w, *ll2_b;
    const u16 *p1_w, *p1_b, *p2_w, *p2_b, *p3_w, *p3_b, *p4_w, *p4_b, *pe_w, *pe_b;
    const u16 *q1_w, *q1_b, *q2_w, *q2_b, *q2e_w, *q2e_b, *q3_w, *q3_b, *q3e_w, *q3e_b;
    // scratch
    unsigned *bar; // [32+bid*16]=arrival slots; [32+NBLK*16+bid*16]=per-block broadcast lines
    int  *flagp;  // [0] = 1 if inputs are float32
    u16 *embs;    // [T][B][96] bf16
    u16 *WgCat;   // [2][2680][768] bf16 : [wi(96) | wh(670) | pad]
    u16 *P1W;     // [512][1472] bf16 (K padded with zeros)
    u16 *W1C;     // [192][672] bf16
    u16 *W2C;     // [10112][192] bf16 : [gl2_w | ll2_w]
    float *BSUM;  // [2][2680] f32 bias sums
    u16 *hs;      // [T][B][672] bf16  (t-major: planes are write-once, line-aligned)
    u16 *hcat;    // [T][B][1344] bf16 (time-indexed -> write-once)
    u16 *uw;      // [5120][192] bf16
    float *ghf, *gcf, *lhf;   // [B][670] f32, same-step only (bypass both ways)
    float *lc2;   // [T][B][670] f32 (time-indexed -> write-once)
    float *gcm;   // [T][B][670] f32 (time-indexed -> write-once)
    float *L1out; // [B][500]
    float *sf;    // [5120][192]
    float *p2sbuf;// [5120][2]
    // normalized bf16 copies of small tensors
    u16 *n_p1b, *n_p2w, *n_p2b, *n_p3w, *n_p3b, *n_p4w, *n_p4b, *n_pew, *n_peb;
    u16 *n_gl1b, *n_ll1b, *n_gl2b, *n_ll2b;
    u16 *n_q1w, *n_q1b, *n_q2w, *n_q2b, *n_q2ew, *n_q2eb, *n_q3w, *n_q3b, *n_q3ew, *n_q3eb;
    u16 *out0, *out1;
    float *out0f, *out1f;
};

// ---------------- software grid barrier: per-block arrival + per-block broadcast ----------------
// Arrival: each block release-stores gen into its own 64B-spaced slot (1 writer, 1 leader-poller
// per line). Leader (block 0) detects all arrivals, then FANS OUT gen to 384 per-block broadcast
// lines (1 writer + 1 poller per line -> no same-line contention, unlike a single shared flag,
// where 383 simultaneous pollers serialize at the coherence point at ~20-30ns each = ~10-20us wake).
template<bool HEAVY>
DI void gbar(unsigned* bar, int bid, int tid, unsigned gen) {
    unsigned* slots = bar + 32;
    unsigned* bcast = bar + 32 + NBLK * 16;
    __syncthreads();                 // compiler drains vmcnt(0) before s_barrier: stores done
    if (tid == 0) {
        if (HEAVY) __threadfence();  // writeback dirty L2 so other XCDs can see cached prep data
        stgu32(&slots[bid * 16], gen);
    }
    if (bid == 0) {
        #pragma unroll 1
        for (int i = tid; i < NBLK; i += 256)
            while ((int)(ldgu32(&slots[i * 16]) - gen) < 0)
                __builtin_amdgcn_s_sleep(1);
        __syncthreads();             // all 384 arrivals seen
        #pragma unroll 1
        for (int i = tid; i < NBLK; i += 256)
            stgu32(&bcast[i * 16], gen);
    } else if (tid == 0) {
        while ((int)(ldgu32(&bcast[bid * 16]) - gen) < 0)
            __builtin_amdgcn_s_sleep(2);
    }
    __syncthreads();
    if (HEAVY) {
        if (tid == 0) __threadfence();   // invalidate local L2 (also clears prev-launch lines)
        __syncthreads();
    }
}

// ------------- detect input dtype + init barrier -------------
__global__ __launch_bounds__(256) void k_detect(Ptrs p) {
    int tid = threadIdx.x;
    for (int i = tid; i < 16384; i += 256) p.bar[i] = 0u;
    if (tid < 64) {
        u32 d = ((const u32*)p.g_bi)[tid];   // first 64 dwords of g_bi
        u16 lo = (u16)(d & 0xffffu);
        int e = (lo >> 7) & 0xff;             // bf16 exponent field of the LOW u16
        unsigned long long m = __ballot(e >= 127);   // |x|>=1 impossible for bf16 N(0,.05) data
        if (tid == 0) p.flagp[0] = (m != 0ull) ? 1 : 0;
    }
}

// ---------------- shared-memory phase overlays ----------------
struct SMg { u16 Al[32 * 72]; u16 Wl[128 * 72]; float bs[128]; };
struct SMm { u16 Al[32 * 72]; u16 Wl[32 * 72]; };
struct SMr { float l1[500]; float h2s[250]; float h3s[100]; float h4s[52]; float pr[4]; };
struct SMs { u16 Al[64 * 40]; u16 Wl[64 * 40]; };
struct SMq {
    float sfl[3840];
    float h1[20][80]; float h2[20][32]; float h3[20][12];
    float yv[20][2]; float zv[20][2]; float p1s[20][2]; float p2sl[20][2];
};
union alignas(16) SMem { SMg g; SMm m; SMr r; SMs s; SMq q; };

// ---------------- phase: normalize small tensors (grid-stride) ----------------
DI void norm_phase(const Ptrs& p, int gtid, int f) {
    const u16* srcs[23] = {p.p1_b, p.p2_w, p.p2_b, p.p3_w, p.p3_b, p.p4_w, p.p4_b,
                           p.pe_w, p.pe_b, p.gl1_b, p.ll1_b, p.gl2_b, p.ll2_b,
                           p.q1_w, p.q1_b, p.q2_w, p.q2_b, p.q2e_w, p.q2e_b,
                           p.q3_w, p.q3_b, p.q3e_w, p.q3e_b};
    u16* dsts[23] = {p.n_p1b, p.n_p2w, p.n_p2b, p.n_p3w, p.n_p3b, p.n_p4w, p.n_p4b,
                     p.n_pew, p.n_peb, p.n_gl1b, p.n_ll1b, p.n_gl2b, p.n_ll2b,
                     p.n_q1w, p.n_q1b, p.n_q2w, p.n_q2b, p.n_q2ew, p.n_q2eb,
                     p.n_q3w, p.n_q3b, p.n_q3ew, p.n_q3eb};
    const int ns[23] = {500, 125000, 250, 25000, 100, 5000, 50, 100, 2, 96, 96, 10004, 10004,
                        14400, 75, 2250, 30, 60, 2, 300, 10, 20, 2};
    for (int i0 = gtid; i0 < 193351; i0 += GT) {
        int i = i0;
        #pragma unroll 1
        for (int s = 0; s < 23; ++s) {
            if (i < ns[s]) { dsts[s][i] = ldw(srcs[s], i, f); break; }
            i -= ns[s];
        }
    }
}

// ---------------- phase: gather embeddings, pack/pad weights (grid-stride) ----------------
DI void prep_one(const Ptrs& p, int i, int f) {
    if (i < 491520) { // embs gather, elementwise
        int r = i / 96, j = i % 96;
        int t = r >> 8, b = r & 255;
        int idx = p.x[b * Tn + t];
        p.embs[r * 96 + j] = ldw(p.emb, (long long)idx * 96 + j, f);
        return;
    }
    i -= 491520;
    if (i < 2 * 2680 * 768) { // WgCat
        int z = i / (2680 * 768);
        int rem = i - z * (2680 * 768);
        int col = rem / 768, k = rem % 768;
        const u16* wi = z ? p.l_wi : p.g_wi;
        const u16* wh = z ? p.l_wh : p.g_wh;
        u16 v = 0;
        if (k < 96) v = ldw(wi, col * 96 + k, f);
        else { int j = k - 96; if (j < 670) v = ldw(wh, col * 670 + j, f); }
        p.WgCat[i] = v;
        return;
    }
    i -= 2 * 2680 * 768;
    if (i < 512 * 1472) { // P1W (K padded to 1472 with zeros)
        int col = i / 1472, k = i % 1472;
        u16 v = 0;
        if (col < 500) {
            if (k < 96) v = ldw(p.p1_w, col * 1436 + k, f);
            else if (k < 768) { int j = k - 96;  if (j < 670) v = ldw(p.p1_w, col * 1436 + 96 + j, f); }
            else              { int j = k - 768; if (j < 670) v = ldw(p.p1_w, col * 1436 + 766 + j, f); }
        }
        p.P1W[i] = v;
        return;
    }
    i -= 512 * 1472;
    if (i < 192 * 672) { // W1C
        int o = i / 672, h = i % 672;
        u16 v = 0;
        if (h < 670) v = (o < 96) ? ldw(p.gl1_w, o * 670 + h, f) : ldw(p.ll1_w, (o - 96) * 670 + h, f);
        p.W1C[i] = v;
        return;
    }
    i -= 192 * 672;
    if (i < 10112 * 192) { // W2C
        int v_ = i / 192, k = i % 192;
        u16 v = 0;
        if (v_ < Vn) v = (k < 96) ? ldw(p.gl2_w, v_ * 96 + k, f) : ldw(p.ll2_w, v_ * 96 + (k - 96), f);
        p.W2C[i] = v;
        return;
    }
    i -= 10112 * 192;
    if (i < 2 * 2680) { // BSUM
        int z = i / 2680, col = i % 2680;
        const u16* bi = z ? p.l_bi : p.g_bi;
        const u16* bh = z ? p.l_bh : p.g_bh;
        p.BSUM[i] = ldf(bi, col, f) + ldf(bh, col, f);
    }
}

// ------------- phase: fused gates GEMM + LSTM elementwise (one tile, BK=64) -------------
// Activations (hs/hcat, write-once planes) read CACHED; state stored via bypass.
DI void gates_tile(const Ptrs& p, int t, int z, int jt, int mt, int tid, SMg& S) {
    const int row0 = mt * 32, j0 = jt * 32;
    const int lane = tid & 63, wv = tid >> 6;

    __syncthreads();
    if (tid < 128) {
        int gate = tid >> 5, jj = tid & 31, j = j0 + jj;
        S.bs[tid] = (j < Hn) ? p.BSUM[z * 2680 + gate * Hn + j] : 0.f;
    }
    f32x4 acc[4] = {};
    const int mtw = wv & 1, jh = wv >> 1;

    for (int kc = 0; kc < 12; ++kc) {
        const int kb = kc * 64;
        __syncthreads();
        #pragma unroll
        for (int it = 0; it < 4; ++it) {
            int idx = tid + it * 256;
            int ri = idx >> 3, k8 = (idx & 7) * 8;
            int gate = ri >> 5, jj = ri & 31, j = j0 + jj;
            u32x4 val = {0, 0, 0, 0};
            if (j < Hn) val = *(const u32x4*)&p.WgCat[(z * 2680 + gate * Hn + j) * 768 + kb + k8];
            *(u32x4*)&S.Wl[ri * 72 + k8] = val;
        }
        {
            int r = tid >> 3, k8 = (tid & 7) * 8, k = kb + k8;
            int b = row0 + r;
            u32x4 val = {0, 0, 0, 0};
            if (k < 96) val = *(const u32x4*)&p.embs[(t * 256 + b) * 96 + k];
            else if (t > 0) {
                int kk = k - 96;
                const u16* src = (z == 0) ? (p.hs + ((t - 1) * B + b) * HP + kk)
                                          : (p.hcat + (t - 1) * (B * 1344) + b * 1344 + 672 + kk);
                val = *(const u32x4*)src;
            }
            *(u32x4*)&S.Al[r * 72 + k8] = val;
        }
        __syncthreads();
        #pragma unroll
        for (int ks = 0; ks < 2; ++ks) {
            bf16x8 a = frag(&S.Al[(mtw * 16 + (lane & 15)) * 72 + ks * 32 + (lane >> 4) * 8]);
            #pragma unroll
            for (int g = 0; g < 4; ++g) {
                int nt = g * 2 + jh;
                bf16x8 bb = frag(&S.Wl[(nt * 16 + (lane & 15)) * 72 + ks * 32 + (lane >> 4) * 8]);
                acc[g] = mfma16(a, bb, acc[g]);
            }
        }
    }
    const int q = lane >> 4;
    const int jj = jh * 16 + (lane & 15);
    const int j = j0 + jj;
    const bool valid = (j < Hn);
    const int b0 = row0 + mtw * 16 + q * 4;
    float cps[4] = {0.f, 0.f, 0.f, 0.f};
    if (valid && t > 0) {
        const float* cb = ((z == 0) ? p.gcm : p.lc2) + (t - 1) * (B * Hn) + j;
        #pragma unroll
        for (int r = 0; r < 4; ++r) cps[r] = cb[(b0 + r) * Hn];   // cached, write-once plane
    }
    #pragma unroll
    for (int r = 0; r < 4; ++r) {
        int b = b0 + r;
        float I = fminf(fmaxf(acc[0][r] + S.bs[jj], -30.f), 30.f);
        float F = fminf(fmaxf(acc[1][r] + S.bs[32 + jj], -30.f), 30.f);
        float G = fminf(fmaxf(acc[2][r] + S.bs[64 + jj], -30.f), 30.f);
        float O = fminf(fmaxf(acc[3][r] + S.bs[96 + jj], -30.f), 30.f);
        float c = sigm(F) * cps[r] + sigm(I) * tanha(G);
        float h = sigm(O) * tanha(c);
        if (z == 0) {
            if (valid) { stg32(&p.ghf[b * Hn + j], h); stg32(&p.gcf[b * Hn + j], c); }
            stg16(&p.hcat[t * (B * 1344) + b * 1344 + j], valid ? f2bf(h) : (u16)0);
        } else {
            if (valid) { stg32(&p.lhf[b * Hn + j], h); stg32(&p.lc2[t * (B * Hn) + b * Hn + j], c); }
            stg16(&p.hcat[t * (B * 1344) + b * 1344 + 672 + j], valid ? f2bf(h) : (u16)0);
        }
    }
}

// ------------- phase: MLP layer 1 GEMM [256,1472]@[1472,512] (128 tiles 32x32, BK=64) -------------
DI void mlp1_tile(const Ptrs& p, int t, int bid, int tid, SMm& S) {
    const int col0 = (bid & 15) * 32;
    const int row0 = (bid >> 4) * 32;
    const int lane = tid & 63, wv = tid >> 6;
    f32x4 acc = {};
    const int mtw = wv & 1, nh = wv >> 1;
    for (int kc = 0; kc < 23; ++kc) {
        const int kb = kc * 64;
        __syncthreads();
        {
            int ri = tid >> 3, k8 = (tid & 7) * 8;
            *(u32x4*)&S.Wl[ri * 72 + k8] = *(const u32x4*)&p.P1W[(col0 + ri) * 1472 + kb + k8];
        }
        {
            int r = tid >> 3, k8 = (tid & 7) * 8, k = kb + k8;
            int b = row0 + r;
            u32x4 val = {0, 0, 0, 0};
            if (k < 96) val = *(const u32x4*)&p.embs[(t * 256 + b) * 96 + k];
            else if (k < 1440) val = *(const u32x4*)&p.hcat[t * (B * 1344) + b * 1344 + (k - 96)];
            *(u32x4*)&S.Al[r * 72 + k8] = val;
        }
        __syncthreads();
        #pragma unroll
        for (int ks = 0; ks < 2; ++ks) {
            bf16x8 a = frag(&S.Al[(mtw * 16 + (lane & 15)) * 72 + ks * 32 + (lane >> 4) * 8]);
            bf16x8 bb = frag(&S.Wl[(nh * 16 + (lane & 15)) * 72 + ks * 32 + (lane >> 4) * 8]);
            acc = mfma16(a, bb, acc);
        }
    }
    const int q = lane >> 4;
    int col = col0 + nh * 16 + (lane & 15);
    if (col < 500) {
        float bias = bf2f(p.n_p1b[col]);
        #pragma unroll
        for (int r = 0; r < 4; ++r) {
            int b = row0 + mtw * 16 + q * 4 + r;
            stg32(&p.L1out[b * 500 + col], fmaxf(acc[r] + bias, 0.f));
        }
    }
}

// ------------- phase: MLP layers 2..5, softmax, mix, write hs/out1 -------------
DI void rest_block(const Ptrs& p, int t, int b, int tid, int f, SMr& S) {
    if (tid < 125) {
        u32x4 v = ldg16(&p.L1out[b * 500 + tid * 4]);
        *(u32x4*)&S.l1[tid * 4] = v;
    }
    __syncthreads();
    if (tid < 250) {
        const u16* wr = p.n_p2w + tid * 500;
        float s = 0.f;
        for (int k = 0; k < 500; k += 4) {
            uint2 u = *(const uint2*)&wr[k];
            s += S.l1[k]     * bf2f((u16)(u.x & 0xffff));
            s += S.l1[k + 1] * bf2f((u16)(u.x >> 16));
            s += S.l1[k + 2] * bf2f((u16)(u.y & 0xffff));
            s += S.l1[k + 3] * bf2f((u16)(u.y >> 16));
        }
        S.h2s[tid] = fmaxf(s + bf2f(p.n_p2b[tid]), 0.f);
    }
    __syncthreads();
    if (tid < 100) {
        const u16* wr = p.n_p3w + tid * 250;
        float s = 0.f;
        for (int k = 0; k < 250; k += 2) {
            u32 u = *(const u32*)&wr[k];
            s += S.h2s[k]     * bf2f((u16)(u & 0xffff));
            s += S.h2s[k + 1] * bf2f((u16)(u >> 16));
        }
        S.h3s[tid] = fmaxf(s + bf2f(p.n_p3b[tid]), 0.f);
    }
    __syncthreads();
    if (tid < 50) {
        const u16* wr = p.n_p4w + tid * 100;
        float s = 0.f;
        for (int k = 0; k < 100; k += 4) {
            uint2 u = *(const uint2*)&wr[k];
            s += S.h3s[k]     * bf2f((u16)(u.x & 0xffff));
            s += S.h3s[k + 1] * bf2f((u16)(u.x >> 16));
            s += S.h3s[k + 2] * bf2f((u16)(u.y & 0xffff));
            s += S.h3s[k + 3] * bf2f((u16)(u.y >> 16));
        }
        S.h4s[tid] = fmaxf(s + bf2f(p.n_p4b[tid]), 0.f);
    }
    __syncthreads();
    if (tid == 0) {
        float e0 = bf2f(p.n_peb[0]), e1 = bf2f(p.n_peb[1]);
        for (int k = 0; k < 50; ++k) {
            e0 += S.h4s[k] * bf2f(p.n_pew[k]);
            e1 += S.h4s[k] * bf2f(p.n_pew[50 + k]);
        }
        float m = fmaxf(e0, e1);
        float a0 = __expf(e0 - m), a1 = __expf(e1 - m);
        float inv = 1.f / (a0 + a1);
        S.pr[0] = a0 * inv; S.pr[1] = a1 * inv;
    }
    __syncthreads();
    float p0 = S.pr[0], p1 = S.pr[1];
    for (int j = tid; j < HP; j += 256) {
        u16 hv = 0;
        if (j < Hn) {
            float lh, gh, lc, gc;
            ldg4f(&p.lhf[b * Hn + j], &p.ghf[b * Hn + j],
                  &p.lc2[t * (B * Hn) + b * Hn + j], &p.gcf[b * Hn + j], lh, gh, lc, gc);
            float gm = p0 * lh + p1 * gh;
            float cm = p0 * lc + p1 * gc;
            stg32(&p.gcm[t * (B * Hn) + b * Hn + j], cm);
            hv = f2bf(gm);
        }
        stg16(&p.hs[(t * B + b) * HP + j], hv);
    }
    if (tid < 40) {
        long long idx = b * 880 + t * 40 + tid;
        float v = (tid & 1) ? p1 : p0;
        if (f) p.out1f[idx] = v; else p.out1[idx] = f2bf(v);
    }
}

// ------------- phase: sf = hs @ [gl1;ll1]^T + bias  ([5120,672]@[672,192]) -------------
DI void sf_tile(const Ptrs& p, int tau, int tid, SMs& S) {
    const int col0 = (tau % 3) * 64;
    const int row0 = (tau / 3) * 64;
    const int lane = tid & 63, wv = tid >> 6;
    // output row n = b*20+t; hs stored t-major: plane t, row b
    const int n = row0 + (tid >> 2);
    const u16* arow = p.hs + ((n % Tn) * B + (n / Tn)) * HP;
    f32x4 acc[4] = {};
    for (int kc = 0; kc < 21; ++kc) {
        const int kb = kc * 32;
        __syncthreads();
        {
            int r = tid >> 2, k8 = (tid & 3) * 8;
            *(u32x4*)&S.Wl[r * 40 + k8] = *(const u32x4*)&p.W1C[(col0 + r) * HP + kb + k8];
            *(u32x4*)&S.Al[r * 40 + k8] = *(const u32x4*)&arow[kb + k8];
        }
        __syncthreads();
        bf16x8 a = frag(&S.Al[(wv * 16 + (lane & 15)) * 40 + (lane >> 4) * 8]);
        #pragma unroll
        for (int nt = 0; nt < 4; ++nt) {
            bf16x8 bb = frag(&S.Wl[(nt * 16 + (lane & 15)) * 40 + (lane >> 4) * 8]);
            acc[nt] = mfma16(a, bb, acc[nt]);
        }
    }
    const int q = lane >> 4;
    #pragma unroll
    for (int nt = 0; nt < 4; ++nt) {
        int col = col0 + nt * 16 + (lane & 15);
        float bias = bf2f(col < 96 ? p.n_gl1b[col] : p.n_ll1b[col - 96]);
        #pragma unroll
        for (int r = 0; r < 4; ++r) {
            int row = row0 + wv * 16 + q * 4 + r;
            stg32(&p.sf[row * 192 + col], acc[nt][r] + bias);
        }
    }
}

// ------------- phase: per-batch q-chain, softmaxes, u/w, out1 rows 20/21 -------------
DI void qchain_block(const Ptrs& p, int b, int tid, int f, SMq& S) {
    for (int i = tid; i < 960; i += 256)
        *(float4*)&S.sfl[i * 4] = *(const float4*)&p.sf[b * 3840 + i * 4];  // cached: sf write-once
    __syncthreads();
    for (int u = tid; u < 1500; u += 256) {
        int row = u / 75, o = u % 75;
        const u16* wr = p.n_q1w + o * 192;
        const float* sr = &S.sfl[row * 192];
        float s = bf2f(p.n_q1b[o]);
        for (int k = 0; k < 192; k += 4) {
            uint2 w = *(const uint2*)&wr[k];
            s += sr[k]     * bf2f((u16)(w.x & 0xffff));
            s += sr[k + 1] * bf2f((u16)(w.x >> 16));
            s += sr[k + 2] * bf2f((u16)(w.y & 0xffff));
            s += sr[k + 3] * bf2f((u16)(w.y >> 16));
        }
        S.h1[row][o] = fmaxf(s, 0.f);
    }
    __syncthreads();
    for (int u = tid; u < 600; u += 256) {
        int row = u / 30, o = u % 30;
        const u16* wr = p.n_q2w + o * 75;
        float s = bf2f(p.n_q2b[o]);
        for (int k = 0; k < 75; ++k) s += S.h1[row][k] * bf2f(wr[k]);
        S.h2[row][o] = fmaxf(s, 0.f);
    }
    __syncthreads();
    if (tid < 40) {
        int row = tid >> 1, o = tid & 1;
        const u16* wr = p.n_q2ew + o * 30;
        float s = bf2f(p.n_q2eb[o]);
        for (int k = 0; k < 30; ++k) s += S.h2[row][k] * bf2f(wr[k]);
        S.yv[row][o] = fmaxf(s, 0.f);
    } else if (tid >= 56 && tid < 256) {
        int u = tid - 56;  // 200 units
        int row = u / 10, o = u % 10;
        const u16* wr = p.n_q3w + o * 30;
        float s = bf2f(p.n_q3b[o]);
        for (int k = 0; k < 30; ++k) s += S.h2[row][k] * bf2f(wr[k]);
        S.h3[row][o] = fmaxf(s, 0.f);
    }
    __syncthreads();
    if (tid < 40) {
        int row = tid >> 1, o = tid & 1;
        const u16* wr = p.n_q3ew + o * 10;
        float s = bf2f(p.n_q3eb[o]);
        for (int k = 0; k < 10; ++k) s += S.h3[row][k] * bf2f(wr[k]);
        S.zv[row][o] = fmaxf(s, 0.f);
    } else if (tid >= 64 && tid < 84) {
        int row = tid - 64;
        float m = fmaxf(S.yv[row][0], S.yv[row][1]);
        float a0 = __expf(S.yv[row][0] - m), a1 = __expf(S.yv[row][1] - m);
        float inv = 1.f / (a0 + a1);
        S.p1s[row][0] = a0 * inv; S.p1s[row][1] = a1 * inv;
    }
    __syncthreads();
    if (tid < 20) {
        float m = fmaxf(S.zv[tid][0], S.zv[tid][1]);
        float a0 = __expf(S.zv[tid][0] - m), a1 = __expf(S.zv[tid][1] - m);
        float inv = 1.f / (a0 + a1);
        S.p2sl[tid][0] = a0 * inv; S.p2sl[tid][1] = a1 * inv;
        p.p2sbuf[(b * Tn + tid) * 2]     = a0 * inv;
        p.p2sbuf[(b * Tn + tid) * 2 + 1] = a1 * inv;
    } else if (tid >= 64 && tid < 104) {
        int row = (tid - 64) >> 1, c = (tid - 64) & 1;
        long long idx = b * 880 + 800 + row * 2 + c;
        if (f) p.out1f[idx] = S.p1s[row][c]; else p.out1[idx] = f2bf(S.p1s[row][c]);
    }
    __syncthreads();
    for (int u = tid; u < 1920; u += 256) {
        int row = u / 96, e = u % 96;
        float xm = S.p1s[row][0] * S.sfl[row * 192 + e] + S.p1s[row][1] * S.sfl[row * 192 + 96 + e];
        p.uw[(b * Tn + row) * 192 + e]      = f2bf(S.p2sl[row][0] * xm);
        p.uw[(b * Tn + row) * 192 + 96 + e] = f2bf(S.p2sl[row][1] * xm);
    }
    if (tid < 40) {
        int row = tid >> 1, c = tid & 1;
        long long idx = b * 880 + 840 + row * 2 + c;
        if (f) p.out1f[idx] = S.p2sl[row][c]; else p.out1[idx] = f2bf(S.p2sl[row][c]);
    }
}

// ------------- the fused kernel -------------
__global__ __launch_bounds__(256, 2) void k_loop(Ptrs p) {
    const int bid = blockIdx.x;
    const int tid = threadIdx.x;
    const int f = p.flagp[0];
    const int gtid = bid * 256 + tid;
    unsigned gen = 0;

    __shared__ SMem sm;

    // phase 0: normalize small tensors + gather/pack
    norm_phase(p, gtid, f);
    #pragma unroll 1
    for (int i0 = gtid; i0 < 7437552; i0 += GT) prep_one(p, i0, f);
    gbar<true>(p.bar, bid, tid, ++gen);   // heavy: publish cached prep + invalidate stale L2 lines

    // XCD-aware gates mapping: all 8 mt-tiles of a (z,jt) pair land on one XCD
    // (bid%8 = XCD); z split by XCD group; per-XCD weight set ~1.15 MB -> L2-resident.
    const int gx = bid & 7, gg = bid >> 3;
    const int gz = gx >> 2, gjt = (gx & 3) * 6 + (gg >> 3), gmt = gg & 7;
    const bool gvalid = (gjt < 21);

    // recurrent loop: 3 phases per step, lite barriers only
    #pragma unroll 1
    for (int t = 0; t < Tn; ++t) {
        if (gvalid) gates_tile(p, t, gz, gjt, gmt, tid, sm.g);
        gbar<false>(p.bar, bid, tid, ++gen);
        if (bid < 128) mlp1_tile(p, t, bid, tid, sm.m);
        gbar<false>(p.bar, bid, tid, ++gen);
        if (bid < 256) rest_block(p, t, bid, tid, f, sm.r);
        gbar<false>(p.bar, bid, tid, ++gen);
    }

    // post: sf GEMM (240 tiles) then per-batch q-chain
    if (bid < 240) sf_tile(p, bid, tid, sm.s);
    gbar<false>(p.bar, bid, tid, ++gen);
    if (bid < 256) qchain_block(p, bid, tid, f, sm.q);
}

// ------------- final GEMM: C[v,(b,t)] = W2C[v,:]·uw[n,:], K=192, out [B][V][T] -------------
__global__ __launch_bounds__(256) void k_final(Ptrs p) {
    const int n0 = blockIdx.x * 64;   // 80 blocks
    const int v0 = blockIdx.y * 128;  // 79 blocks
    const int tid = threadIdx.x, lane = tid & 63, wv = tid >> 6;
    const int f = p.flagp[0];
    __shared__ u16 Wl[128 * 104];
    __shared__ u16 Ul[64 * 104];
    f32x4 acc[2][4] = {};
    const int m = lane & 15, q = lane >> 4;
    for (int kc = 0; kc < 2; ++kc) {
        const int kb = kc * 96;
        __syncthreads();
        for (int i = tid; i < 1536; i += 256) {
            int ri = i / 12, k8 = (i % 12) * 8;
            *(uint4*)&Wl[ri * 104 + k8] = *(const uint4*)&p.W2C[(v0 + ri) * 192 + kb + k8];
        }
        for (int i = tid; i < 768; i += 256) {
            int ri = i / 12, k8 = (i % 12) * 8;
            *(uint4*)&Ul[ri * 104 + k8] = *(const uint4*)&p.uw[(n0 + ri) * 192 + kb + k8];
        }
        __syncthreads();
        #pragma unroll
        for (int ks = 0; ks < 3; ++ks) {
            int ko = ks * 32 + q * 8;
            bf16x8 a0 = frag(&Wl[(wv * 32 + m) * 104 + ko]);
            bf16x8 a1 = frag(&Wl[(wv * 32 + 16 + m) * 104 + ko]);
            #pragma unroll
            for (int ni = 0; ni < 4; ++ni) {
                bf16x8 bb = frag(&Ul[(ni * 16 + m) * 104 + ko]);
                acc[0][ni] = mfma16(a0, bb, acc[0][ni]);
                acc[1][ni] = mfma16(a1, bb, acc[1][ni]);
            }
        }
    }
    #pragma unroll
    for (int ni = 0; ni < 4; ++ni) {
        int n = n0 + ni * 16 + m;
        int bb = n / 20, tt = n % 20;
        float s0 = p.p2sbuf[n * 2], s1 = p.p2sbuf[n * 2 + 1];
        size_t base = (size_t)bb * 200080 + tt;
        #pragma unroll
        for (int mi = 0; mi < 2; ++mi) {
            #pragma unroll
            for (int r = 0; r < 4; ++r) {
                int v = v0 + wv * 32 + mi * 16 + q * 4 + r;
                if (v < Vn) {
                    float val = acc[mi][ni][r] + s0 * bf2f(p.n_gl2b[v]) + s1 * bf2f(p.n_ll2b[v]);
                    size_t idx = base + (size_t)v * 20;
                    if (f) p.out0f[idx] = val; else p.out0[idx] = f2bf(val);
                }
            }
        }
    }
}

extern "C" void kernel_launch(void* const* d_in, const int* in_sizes, int n_in,
                              void* d_out, int out_size, void* d_ws, size_t ws_size,
                              hipStream_t stream) {
    Ptrs p;
    p.x    = (const int*)d_in[0];
    p.emb  = (const u16*)d_in[1];
    p.g_wi = (const u16*)d_in[2];  p.g_wh = (const u16*)d_in[3];
    p.g_bi = (const u16*)d_in[4];  p.g_bh = (const u16*)d_in[5];
    p.l_wi = (const u16*)d_in[6];  p.l_wh = (const u16*)d_in[7];
    p.l_bi = (const u16*)d_in[8];  p.l_bh = (const u16*)d_in[9];
    p.gl1_w = (const u16*)d_in[10]; p.gl1_b = (const u16*)d_in[11];
    p.ll1_w = (const u16*)d_in[12]; p.ll1_b = (const u16*)d_in[13];
    p.gl2_w = (const u16*)d_in[14]; p.gl2_b = (const u16*)d_in[15];
    p.ll2_w = (const u16*)d_in[16]; p.ll2_b = (const u16*)d_in[17];
    p.p1_w = (const u16*)d_in[18]; p.p1_b = (const u16*)d_in[19];
    p.p2_w = (const u16*)d_in[20]; p.p2_b = (const u16*)d_in[21];
    p.p3_w = (const u16*)d_in[22]; p.p3_b = (const u16*)d_in[23];
    p.p4_w = (const u16*)d_in[24]; p.p4_b = (const u16*)d_in[25];
    p.pe_w = (const u16*)d_in[26]; p.pe_b = (const u16*)d_in[27];
    p.q1_w = (const u16*)d_in[28]; p.q1_b = (const u16*)d_in[29];
    p.q2_w = (const u16*)d_in[30]; p.q2_b = (const u16*)d_in[31];
    p.q2e_w = (const u16*)d_in[32]; p.q2e_b = (const u16*)d_in[33];
    p.q3_w = (const u16*)d_in[34]; p.q3_b = (const u16*)d_in[35];
    p.q3e_w = (const u16*)d_in[36]; p.q3e_b = (const u16*)d_in[37];

    char* w = (char*)d_ws;
    auto carve = [&](size_t bytes) { char* r = w; w += (bytes + 255) & ~(size_t)255; return r; };
    p.bar    = (unsigned*)carve(65536);
    p.flagp  = (int*)carve(256);
    p.embs   = (u16*)carve((size_t)20 * 256 * 96 * 2);
    p.WgCat  = (u16*)carve((size_t)2 * 2680 * 768 * 2);
    p.P1W    = (u16*)carve((size_t)512 * 1472 * 2);
    p.W1C    = (u16*)carve((size_t)192 * 672 * 2);
    p.W2C    = (u16*)carve((size_t)10112 * 192 * 2);
    p.BSUM   = (float*)carve((size_t)2 * 2680 * 4);
    p.hs     = (u16*)carve((size_t)20 * 256 * 672 * 2);
    p.hcat   = (u16*)carve((size_t)20 * 256 * 1344 * 2);
    p.uw     = (u16*)carve((size_t)5120 * 192 * 2);
    p.ghf    = (float*)carve((size_t)256 * 670 * 4);
    p.gcf    = (float*)carve((size_t)256 * 670 * 4);
    p.lhf    = (float*)carve((size_t)256 * 670 * 4);
    p.lc2    = (float*)carve((size_t)20 * 256 * 670 * 4);
    p.gcm    = (float*)carve((size_t)20 * 256 * 670 * 4);
    p.L1out  = (float*)carve((size_t)256 * 500 * 4);
    p.sf     = (float*)carve((size_t)5120 * 192 * 4);
    p.p2sbuf = (float*)carve((size_t)5120 * 2 * 4);
    p.n_p1b = (u16*)carve(500 * 2);   p.n_p2w = (u16*)carve(125000 * 2);
    p.n_p2b = (u16*)carve(250 * 2);   p.n_p3w = (u16*)carve(25000 * 2);
    p.n_p3b = (u16*)carve(100 * 2);   p.n_p4w = (u16*)carve(5000 * 2);
    p.n_p4b = (u16*)carve(50 * 2);    p.n_pew = (u16*)carve(100 * 2);
    p.n_peb = (u16*)carve(2 * 2);
    p.n_gl1b = (u16*)carve(96 * 2);   p.n_ll1b = (u16*)carve(96 * 2);
    p.n_gl2b = (u16*)carve(10004 * 2); p.n_ll2b = (u16*)carve(10004 * 2);
    p.n_q1w = (u16*)carve(14400 * 2); p.n_q1b = (u16*)carve(75 * 2);
    p.n_q2w = (u16*)carve(2250 * 2);  p.n_q2b = (u16*)carve(30 * 2);
    p.n_q2ew = (u16*)carve(60 * 2);   p.n_q2eb = (u16*)carve(2 * 2);
    p.n_q3w = (u16*)carve(300 * 2);   p.n_q3b = (u16*)carve(10 * 2);
    p.n_q3ew = (u16*)carve(20 * 2);   p.n_q3eb = (u16*)carve(2 * 2);
    p.out0 = (u16*)d_out;
    p.out1 = p.out0 + 51220480;
    p.out0f = (float*)d_out;
    p.out1f = p.out0f + 51220480;

    k_detect<<<1, 256, 0, stream>>>(p);
    k_loop<<<NBLK, 256, 0, stream>>>(p);
    k_final<<<dim3(80, 79), 256, 0, stream>>>(p);
}